// Round 17
// baseline (124.086 us; speedup 1.0000x reference)
//
#include <hip/hip_runtime.h>
#include <math.h>

// DifferentiableLassoSelector: B=65536, n=256, h=32.
// p = 6553.6 - Z^T y > 0 elementwise (~40 sigma margin) => projected-gradient
// QP stays at lam=0 exactly => y_hat = 0 exactly.
// Chebyshev factorization, h pre-combined: C_k[n] = sum_h W2 c_k[n,h];
// z~[b,n] = sum_k C_k T_k(x/X); zty[n] = sum_b y z~.
// r16 post-mortem: compiler CHOSE VGPR=32 (8-wave heuristic) and serialized
// the upfront loads + rematerialized constants -> 100us. r17: same structure
// with liveness PINNED: sched_barrier(0) after the load block + one asm
// keep-alive naming all 37 values (forces >=37 simultaneous VGPRs), under
// (256,3) cap 85. Certification gates the zero path; exact fallback is one
// flag-guarded kernel (last-block-done ticket).

#define NF 256
#define HID 32
#define BATCHN 65536
#define ALPHA_BF 6553.6f               // ALPHA * BATCH
#define JITTERF 1e-4f
#define QP_ITERS_N 500
#define K2C 2.8853900817779268f        // 2*log2(e): exp2(K2C*u) = e^{2u}
#define XFIX 6.5f
#define INVX (1.0f / 6.5f)
#define NNODE 44                       // Chebyshev nodes; coeffs k=0..43
// ws float layout:
// 0: flagA | 1: Xobs bits | 2: ticket | 8..72: ypart[64] | 72..136: yabspart
// 256:     Carr[21][256]     -> 5632
// 5632:    tailpart[23][256] -> 11520
// 11520:   sw2[256]          -> 11776
// 12288:   part2[64][256]    -> 28672
// 28672:   part[8192][256]   -> 2125824
// 2125824: fb_part[2048][256]-> 2650112
// 2650112: p_ex[256]         -> 2650368
// 2650368: Q | L | Qe        -> 2846976  (~11.4 MB total)

#if __has_builtin(__builtin_amdgcn_exp2f)
__device__ __forceinline__ float fexp2(float x) { return __builtin_amdgcn_exp2f(x); }
#else
__device__ __forceinline__ float fexp2(float x) { return exp2f(x); }
#endif
#if __has_builtin(__builtin_amdgcn_rcpf)
__device__ __forceinline__ float frcp(float x) { return __builtin_amdgcn_rcpf(x); }
#else
__device__ __forceinline__ float frcp(float x) { return 1.0f / x; }
#endif

// exact per-feature MLP output z[b,n] (fallback path only; perf-irrelevant)
__device__ __forceinline__ float zeval(const float* __restrict__ W1,
                                       const float* __restrict__ b1,
                                       const float* __restrict__ W2,
                                       const float* __restrict__ b2,
                                       int n, float xv)
{
  float acc = b2[n];
  for (int h = 0; h < HID; ++h) {
    float u  = fmaf(xv, W1[n * HID + h], b1[n * HID + h]);
    float th = fmaf(-2.f, frcp(fexp2(K2C * u) + 1.f), 1.f);   // exact tanh
    acc = fmaf(W2[n * HID + h], th, acc);
  }
  return acc;
}

// ---------------- mcoeff: ysum (blocks 0..63) + combined coeffs (64..1471) ---
__global__ __launch_bounds__(256) void mcoeff_kernel(
    const float* __restrict__ y,
    const float* __restrict__ W1, const float* __restrict__ b1,
    const float* __restrict__ W2, float* __restrict__ wsf)
{
  const int t = threadIdx.x;
  if ((int)blockIdx.x < 64) {
    // ---- ysum role: per-block partial sums of y and |y| ----
    const int gi = blockIdx.x * 256 + t;
    if (gi == 0) wsf[1] = 0.f;                  // Xobs (atomicMax target)
    if (gi == 2) wsf[2] = 0.f;                  // fallback ticket
    float4 v = *reinterpret_cast<const float4*>(y + gi * 4);
    float s  = (v.x + v.y) + (v.z + v.w);
    float sa = (fabsf(v.x) + fabsf(v.y)) + (fabsf(v.z) + fabsf(v.w));
    #pragma unroll
    for (int m = 1; m < 64; m <<= 1) {
      s  += __shfl_xor(s, m);
      sa += __shfl_xor(sa, m);
    }
    __shared__ float ls[4], la[4];
    int w = t >> 6;
    if ((t & 63) == 0) { ls[w] = s; la[w] = sa; }
    __syncthreads();
    if (t == 0) {
      wsf[8  + blockIdx.x] = (ls[0] + ls[1]) + (ls[2] + ls[3]);
      wsf[72 + blockIdx.x] = (la[0] + la[1]) + (la[2] + la[3]);
    }
  } else {
    // ---- coeff role: thread = (id, k); h-reduced combined coefficients ----
    const int cb = blockIdx.x - 64;            // [0, 1408)
    const int k  = cb >> 5;                    // 0..43
    const int id = (cb & 31) * 256 + t;        // 0..8191 = n*32+h
    const int h  = t & 31;
    const int n  = id >> 5;
    const float aX  = W1[id] * XFIX;
    const float bb  = b1[id];
    const float w2v = W2[id];
    const float kf = (float)k;
    const float C1 = (float)(M_PI / (double)NNODE);
    float acc = 0.f;
    #pragma unroll 4
    for (int jn = 0; jn < NNODE; ++jn) {
      float ang = ((float)jn + 0.5f) * C1;
      float tj  = __cosf(ang);
      float u   = fmaf(aX, tj, bb);
      float f   = fmaf(-2.f, frcp(fexp2(K2C * u) + 1.f), 1.f);  // exact tanh
      acc = fmaf(f, __cosf(kf * ang), acc);
    }
    const float ck = acc * ((k == 0) ? (1.0f / (float)NNODE)
                                     : (2.0f / (float)NNODE));
    float comb = w2v * ck;                     // signed, for C_k[n]
    float cabs = fabsf(comb);                  // |W2 c_k|, for tail
    float wabs = fabsf(w2v);                   // |W2|, for k==0 slack
    #pragma unroll
    for (int m = 1; m < 32; m <<= 1) {         // reduce over h (32 lanes)
      comb += __shfl_xor(comb, m);
      cabs += __shfl_xor(cabs, m);
      wabs += __shfl_xor(wabs, m);
    }
    if (h == 0) {
      if (k <= 20) wsf[256 + k * 256 + n] = comb;
      else         wsf[5632 + (k - 21) * 256 + n] = cabs;
      if (k == 0)  wsf[11520 + n] = wabs;
    }
  }
}

// ---------------- zmom: 8 rows/thread, loads PINNED in flight, (256,3) -------
#define STEPP(CK) { \
  float q0 = fmaf(d0, cc0, -m0), q1 = fmaf(d1, cc1, -m1); \
  a0 = fmaf(CK, q0, a0); a1 = fmaf(CK, q1, a1); \
  m0 = cc0; cc0 = q0; m1 = cc1; cc1 = q1; }

#define PAIR(XA, YA, XB, YB) { \
  mx = fmaxf(mx, fmaxf(fabsf(XA), fabsf(XB))); \
  float h0 = (XA) * INVX, h1 = (XB) * INVX; \
  float d0 = h0 + h0, d1 = h1 + h1; \
  float m0 = 1.f, m1 = 1.f, cc0 = h0, cc1 = h1; \
  float a0 = fmaf(c01, h0, c00), a1 = fmaf(c01, h1, c00); \
  STEPP(c02) STEPP(c03) STEPP(c04) STEPP(c05) STEPP(c06) STEPP(c07) \
  STEPP(c08) STEPP(c09) STEPP(c10) STEPP(c11) STEPP(c12) STEPP(c13) \
  STEPP(c14) STEPP(c15) STEPP(c16) STEPP(c17) STEPP(c18) STEPP(c19) \
  STEPP(c20) \
  z0 = fmaf(a0, (YA), z0); z1 = fmaf(a1, (YB), z1); }

__global__ __launch_bounds__(256, 3) void zmom_kernel(
    const float* __restrict__ x, const float* __restrict__ y,
    float* __restrict__ wsf)
{
  const int t = threadIdx.x;                // feature n == t
  const int blk = blockIdx.x;               // 8192 blocks
  // issue ALL 8 x-loads + 8 y-loads + 21 coeff loads first
  const float* base = x + (size_t)blk * NF + t;
  const size_t S = (size_t)8192 * NF;
  float x0 = base[0],     x1 = base[S];
  float x2 = base[2 * S], x3 = base[3 * S];
  float x4 = base[4 * S], x5 = base[5 * S];
  float x6 = base[6 * S], x7 = base[7 * S];
  float y0 = y[blk],            y1 = y[blk + 8192];
  float y2 = y[blk + 2 * 8192], y3 = y[blk + 3 * 8192];
  float y4 = y[blk + 4 * 8192], y5 = y[blk + 5 * 8192];
  float y6 = y[blk + 6 * 8192], y7 = y[blk + 7 * 8192];
  const float* Carr = wsf + 256;
  float c00 = Carr[t],            c01 = Carr[256 + t];
  float c02 = Carr[512 + t],      c03 = Carr[768 + t];
  float c04 = Carr[1024 + t],     c05 = Carr[1280 + t];
  float c06 = Carr[1536 + t],     c07 = Carr[1792 + t];
  float c08 = Carr[2048 + t],     c09 = Carr[2304 + t];
  float c10 = Carr[2560 + t],     c11 = Carr[2816 + t];
  float c12 = Carr[3072 + t],     c13 = Carr[3328 + t];
  float c14 = Carr[3584 + t],     c15 = Carr[3840 + t];
  float c16 = Carr[4096 + t],     c17 = Carr[4352 + t];
  float c18 = Carr[4608 + t],     c19 = Carr[4864 + t];
  float c20 = Carr[5120 + t];
  // PIN: no compute hoisted above, no load sunk below this point
  __builtin_amdgcn_sched_barrier(0);
  // keep-alive use-point: all 37 values simultaneously live => regalloc must
  // give them distinct VGPRs (defeats the 32-reg serialize/remat heuristic)
  asm volatile("" ::
      "v"(x0), "v"(x1), "v"(x2), "v"(x3),
      "v"(x4), "v"(x5), "v"(x6), "v"(x7),
      "v"(y0), "v"(y1), "v"(y2), "v"(y3),
      "v"(y4), "v"(y5), "v"(y6), "v"(y7),
      "v"(c00), "v"(c01), "v"(c02), "v"(c03), "v"(c04), "v"(c05),
      "v"(c06), "v"(c07), "v"(c08), "v"(c09), "v"(c10), "v"(c11),
      "v"(c12), "v"(c13), "v"(c14), "v"(c15), "v"(c16), "v"(c17),
      "v"(c18), "v"(c19), "v"(c20));
  float z0 = 0.f, z1 = 0.f, mx = 0.f;
  PAIR(x0, y0, x1, y1)
  PAIR(x2, y2, x3, y3)
  PAIR(x4, y4, x5, y5)
  PAIR(x6, y6, x7, y7)
  // |x| max: wave-reduce, block-reduce, ONE atomic per block (order-exact)
  #pragma unroll
  for (int m = 1; m < 64; m <<= 1) mx = fmaxf(mx, __shfl_xor(mx, m));
  __shared__ float wmx[4];
  if ((t & 63) == 0) wmx[t >> 6] = mx;
  __syncthreads();
  if (t == 0) {
    float m4 = fmaxf(fmaxf(wmx[0], wmx[1]), fmaxf(wmx[2], wmx[3]));
    atomicMax(reinterpret_cast<unsigned int*>(&wsf[1]), __float_as_uint(m4));
  }
  wsf[28672 + (size_t)blk * NF + t] = z0 + z1;    // coalesced 1KB/blk
}

// ---------------- red1f: part[8192][256] -> part2[64][256] -------------------
__global__ __launch_bounds__(256) void red1f_kernel(float* __restrict__ wsf)
{
  const int n = threadIdx.x, j = blockIdx.x;      // 64 blocks x 128 slices
  const float* p = wsf + 28672 + (size_t)j * 128 * NF + n;
  float s0 = 0.f, s1 = 0.f, s2 = 0.f, s3 = 0.f;
  for (int k = 0; k < 128; k += 4) {
    s0 += p[(size_t)k * NF];       s1 += p[(size_t)(k + 1) * NF];
    s2 += p[(size_t)(k + 2) * NF]; s3 += p[(size_t)(k + 3) * NF];
  }
  wsf[12288 + (size_t)j * NF + n] = (s0 + s1) + (s2 + s3);
}

// ---------------- zwflag: redundant flag computation + zero-write ------------
__global__ __launch_bounds__(256) void zwflag_kernel(
    const float* __restrict__ b2, float* __restrict__ wsf,
    float* __restrict__ out)
{
  const int t = threadIdx.x;                      // t == feature n
  __shared__ float shv[2];
  if (t < 64) {
    float a = wsf[8 + t], bb = wsf[72 + t];
    #pragma unroll
    for (int m = 1; m < 64; m <<= 1) {
      a  += __shfl_xor(a, m);
      bb += __shfl_xor(bb, m);
    }
    if (t == 0) { shv[0] = a; shv[1] = bb; }
  }
  __syncthreads();
  const float Sy = shv[0], SyA = shv[1];
  float s = 0.f;
  #pragma unroll
  for (int j = 0; j < 64; ++j) s += wsf[12288 + j * NF + t];
  float tailn = 0.f;
  #pragma unroll
  for (int q = 0; q < 23; ++q) tailn += wsf[5632 + q * 256 + t];
  float ptil = ALPHA_BF - (s + b2[t] * Sy);
  float cert = fmaf(fmaf(3.0f, tailn, 3e-3f * wsf[11520 + t]), SyA, 128.0f);
  int ok = ((ptil - cert) >= 0.f) ? 1 : 0;        // NaN -> 0
  __shared__ int smi[256];
  __shared__ int okk;
  smi[t] = ok;
  __syncthreads();
  for (int off = 128; off > 0; off >>= 1) {
    if (t < off) smi[t] = smi[t] & smi[t + off];
    __syncthreads();
  }
  if (t == 0) {
    float Xo = __uint_as_float(*reinterpret_cast<unsigned int*>(&wsf[1]));
    okk = (smi[0] && (Xo <= XFIX)) ? 1 : 0;
    if (blockIdx.x == 0) wsf[0] = okk ? 1.f : 0.f;   // flag for fallback
  }
  __syncthreads();
  if (!okk) return;
  int i = blockIdx.x * 256 + t;                   // 257 blocks = 65792 exactly
  if (i < BATCHN + NF) out[i] = 0.f;              // exact zeros
}

// ---------------- fb_all: entire exact fallback in ONE node ------------------
// flag==1 (always, for bench inputs): every block exits immediately.
// flag==0: 2048 blocks compute exact zty partials; the LAST block to finish
// (device-scope ticket) serially completes p, Q, Cholesky, QP, yhat.
// Correctness-only path -- speed irrelevant; no spin-waits (deadlock-free).
__global__ __launch_bounds__(256) void fb_all_kernel(
    const float* __restrict__ x, const float* __restrict__ y,
    const float* __restrict__ W1, const float* __restrict__ b1,
    const float* __restrict__ W2, const float* __restrict__ b2,
    float* __restrict__ wsf, float* __restrict__ out)
{
  if (wsf[0] >= 0.5f) return;                     // certified zero path taken
  const int t = threadIdx.x;
  float* fb_part = wsf + 2125824;
  float* p_ex    = wsf + 2650112;
  float* Q       = wsf + 2650368;
  float* L       = Q + 65536;
  float* Qe      = L + 65536;
  // phase 1: exact Z^T y partials (32 rows per block)
  {
    const int b0 = blockIdx.x * 32;
    float zty = 0.f;
    for (int r = 0; r < 32; ++r) {
      float xv = x[(size_t)(b0 + r) * NF + t];
      zty = fmaf(zeval(W1, b1, W2, b2, t, xv), y[b0 + r], zty);
    }
    fb_part[(size_t)blockIdx.x * NF + t] = zty;
  }
  __threadfence();
  __shared__ unsigned int tick;
  if (t == 0)
    tick = atomicAdd(reinterpret_cast<unsigned int*>(&wsf[2]), 1u);
  __syncthreads();
  if (tick != 2047u) return;
  // ---- last block: serial completion ----
  {
    float s = 0.f;
    for (int j = 0; j < 2048; ++j) s += fb_part[(size_t)j * NF + t];
    p_ex[t] = ALPHA_BF - s;
  }
  for (int i = t; i < 65536; i += 256)
    Q[i] = ((i >> 8) == (i & 255)) ? JITTERF : 0.f;
  __syncthreads();
  __shared__ float zsh[16 * NF];                  // 16 KiB chunks of Z
  for (int c = 0; c < BATCHN / 16; ++c) {
    const int r0 = c * 16;
    for (int r = 0; r < 16; ++r)
      zsh[r * NF + t] = zeval(W1, b1, W2, b2, t, x[(size_t)(r0 + r) * NF + t]);
    __syncthreads();
    for (int j = 0; j < NF; ++j) {
      float s = 0.f;
      for (int r = 0; r < 16; ++r) s += zsh[r * NF + t] * zsh[r * NF + j];
      Q[t * NF + j] += s;
    }
    __syncthreads();
  }
  // right-looking Cholesky -> Qe = L L^T
  __shared__ float sm[NF];
  __shared__ float lam_s[NF];
  for (int i = 0; i < NF; ++i) L[i * NF + t] = (t <= i) ? Q[i * NF + t] : 0.f;
  __syncthreads();
  for (int k = 0; k < NF; ++k) {
    if (t == 0) L[k * NF + k] = sqrtf(L[k * NF + k]);
    __syncthreads();
    float lkk = L[k * NF + k];
    if (t > k) L[t * NF + k] /= lkk;
    __syncthreads();
    if (t > k) {
      float ltk = L[t * NF + k];
      for (int i = k + 1; i <= t; ++i) L[t * NF + i] -= ltk * L[i * NF + k];
    }
    __syncthreads();
  }
  for (int i = 0; i < NF; ++i) {
    int m = (i < t) ? i : t;
    float s = 0.f;
    for (int k = 0; k <= m; ++k) s += L[i * NF + k] * L[t * NF + k];
    Qe[i * NF + t] = s;
  }
  __syncthreads();
  lam_s[t] = 1.f;
  __syncthreads();
  float lmax = 1.f;
  for (int it = 0; it < 256; ++it) {              // power iteration
    float s = 0.f;
    for (int k = 0; k < NF; ++k) s += Qe[t * NF + k] * lam_s[k];
    sm[t] = s * s;
    __syncthreads();
    for (int off = 128; off > 0; off >>= 1) {
      if (t < off) sm[t] += sm[t + off];
      __syncthreads();
    }
    float nrm = sqrtf(sm[0]);
    __syncthreads();
    lam_s[t] = s / nrm;
    lmax = nrm;
    __syncthreads();
  }
  float step = 1.0f / lmax;
  lam_s[t] = 0.f;
  __syncthreads();
  float pv = p_ex[t];
  for (int it = 0; it < QP_ITERS_N; ++it) {       // projected gradient
    float s = 0.f;
    for (int k = 0; k < NF; ++k) s += Qe[t * NF + k] * lam_s[k];
    float ln = fmaxf(lam_s[t] - step * (s + pv), 0.f);
    __syncthreads();
    lam_s[t] = ln;
    __syncthreads();
  }
  out[BATCHN + t] = lam_s[t];
  __syncthreads();
  for (int b = t; b < BATCHN; b += 256) {         // y_hat = Z @ lam
    float acc = 0.f;
    for (int n = 0; n < NF; ++n)
      acc = fmaf(zeval(W1, b1, W2, b2, n, x[(size_t)b * NF + n]),
                 lam_s[n], acc);
    out[b] = acc;
  }
}

// ---------------- host launcher ---------------------------------------------
extern "C" void kernel_launch(void* const* d_in, const int* in_sizes, int n_in,
                              void* d_out, int out_size, void* d_ws, size_t ws_size,
                              hipStream_t stream) {
  const float* x  = (const float*)d_in[0];
  const float* y  = (const float*)d_in[1];
  const float* W1 = (const float*)d_in[2];
  const float* b1 = (const float*)d_in[3];
  const float* W2 = (const float*)d_in[4];
  const float* b2 = (const float*)d_in[5];
  float* out = (float*)d_out;            // [0,65536): y_hat ; [65536,65792): lam
  float* ws  = (float*)d_ws;

  // fast certified path (4 nodes) + single-node fallback
  mcoeff_kernel<<<1472, 256, 0, stream>>>(y, W1, b1, W2, ws);
  zmom_kernel<<<8192, 256, 0, stream>>>(x, y, ws);
  red1f_kernel<<<64, 256, 0, stream>>>(ws);
  zwflag_kernel<<<257, 256, 0, stream>>>(b2, ws, out);
  fb_all_kernel<<<2048, 256, 0, stream>>>(x, y, W1, b1, W2, b2, ws, out);
}

// Round 18
// 79.113 us; speedup vs baseline: 1.5685x; 1.5685x over previous
//
#include <hip/hip_runtime.h>
#include <math.h>

// DifferentiableLassoSelector: B=65536, n=256, h=32.
// p = 6553.6 - Z^T y > 0 elementwise (~40 sigma margin) => projected-gradient
// QP stays at lam=0 exactly => y_hat = 0 exactly.
// Chebyshev factorization, h pre-combined: C_k[n] = sum_h W2 c_k[n,h];
// z~[b,n] = sum_k C_k T_k(x/X); zty[n] = sum_b y z~.
// r16/r17 post-mortem: straight-line "all loads up front" gets VGPR=32 +
// serialized loads (100us) regardless of pins; the ROLLING pipeline form
// (r13/r14) is the only shape regalloc allocates honestly (VGPR 44, ~38us).
// r18: restore r14's rolling depth-4 2-feat/lane zmom, ONE change: 4096
// blocks x 8 rows/thread (16 blocks/CU, 2x resident waves for latency
// overlap). Certification gates the zero path; exact fallback is one
// flag-guarded kernel (last-block-done ticket).

#define NF 256
#define HID 32
#define BATCHN 65536
#define ALPHA_BF 6553.6f               // ALPHA * BATCH
#define JITTERF 1e-4f
#define QP_ITERS_N 500
#define K2C 2.8853900817779268f        // 2*log2(e): exp2(K2C*u) = e^{2u}
#define XFIX 6.5f
#define INVX (1.0f / 6.5f)
#define NNODE 44                       // Chebyshev nodes; coeffs k=0..43
// ws float layout:
// 0: flagA | 1: Xobs bits | 2: ticket | 8..72: ypart[64] | 72..136: yabspart
// 256:     Carr[21][256]     -> 5632
// 5632:    tailpart[23][256] -> 11520
// 11520:   sw2[256]          -> 11776
// 12288:   part2[64][256]    -> 28672
// 28672:   part[4096][256]   -> 1077248
// 1077248: fb_part[2048][256]-> 1601536
// 1601536: p_ex[256]         -> 1601792
// 1601792: Q | L | Qe        -> 1798400  (~7.2 MB total)

#if __has_builtin(__builtin_amdgcn_exp2f)
__device__ __forceinline__ float fexp2(float x) { return __builtin_amdgcn_exp2f(x); }
#else
__device__ __forceinline__ float fexp2(float x) { return exp2f(x); }
#endif
#if __has_builtin(__builtin_amdgcn_rcpf)
__device__ __forceinline__ float frcp(float x) { return __builtin_amdgcn_rcpf(x); }
#else
__device__ __forceinline__ float frcp(float x) { return 1.0f / x; }
#endif

// exact per-feature MLP output z[b,n] (fallback path only; perf-irrelevant)
__device__ __forceinline__ float zeval(const float* __restrict__ W1,
                                       const float* __restrict__ b1,
                                       const float* __restrict__ W2,
                                       const float* __restrict__ b2,
                                       int n, float xv)
{
  float acc = b2[n];
  for (int h = 0; h < HID; ++h) {
    float u  = fmaf(xv, W1[n * HID + h], b1[n * HID + h]);
    float th = fmaf(-2.f, frcp(fexp2(K2C * u) + 1.f), 1.f);   // exact tanh
    acc = fmaf(W2[n * HID + h], th, acc);
  }
  return acc;
}

// ---------------- mcoeff: ysum (blocks 0..63) + combined coeffs (64..1471) ---
__global__ __launch_bounds__(256) void mcoeff_kernel(
    const float* __restrict__ y,
    const float* __restrict__ W1, const float* __restrict__ b1,
    const float* __restrict__ W2, float* __restrict__ wsf)
{
  const int t = threadIdx.x;
  if ((int)blockIdx.x < 64) {
    // ---- ysum role: per-block partial sums of y and |y| ----
    const int gi = blockIdx.x * 256 + t;
    if (gi == 0) wsf[1] = 0.f;                  // Xobs (atomicMax target)
    if (gi == 2) wsf[2] = 0.f;                  // fallback ticket
    float4 v = *reinterpret_cast<const float4*>(y + gi * 4);
    float s  = (v.x + v.y) + (v.z + v.w);
    float sa = (fabsf(v.x) + fabsf(v.y)) + (fabsf(v.z) + fabsf(v.w));
    #pragma unroll
    for (int m = 1; m < 64; m <<= 1) {
      s  += __shfl_xor(s, m);
      sa += __shfl_xor(sa, m);
    }
    __shared__ float ls[4], la[4];
    int w = t >> 6;
    if ((t & 63) == 0) { ls[w] = s; la[w] = sa; }
    __syncthreads();
    if (t == 0) {
      wsf[8  + blockIdx.x] = (ls[0] + ls[1]) + (ls[2] + ls[3]);
      wsf[72 + blockIdx.x] = (la[0] + la[1]) + (la[2] + la[3]);
    }
  } else {
    // ---- coeff role: thread = (id, k); h-reduced combined coefficients ----
    const int cb = blockIdx.x - 64;            // [0, 1408)
    const int k  = cb >> 5;                    // 0..43
    const int id = (cb & 31) * 256 + t;        // 0..8191 = n*32+h
    const int h  = t & 31;
    const int n  = id >> 5;
    const float aX  = W1[id] * XFIX;
    const float bb  = b1[id];
    const float w2v = W2[id];
    const float kf = (float)k;
    const float C1 = (float)(M_PI / (double)NNODE);
    float acc = 0.f;
    #pragma unroll 4
    for (int jn = 0; jn < NNODE; ++jn) {
      float ang = ((float)jn + 0.5f) * C1;
      float tj  = __cosf(ang);
      float u   = fmaf(aX, tj, bb);
      float f   = fmaf(-2.f, frcp(fexp2(K2C * u) + 1.f), 1.f);  // exact tanh
      acc = fmaf(f, __cosf(kf * ang), acc);
    }
    const float ck = acc * ((k == 0) ? (1.0f / (float)NNODE)
                                     : (2.0f / (float)NNODE));
    float comb = w2v * ck;                     // signed, for C_k[n]
    float cabs = fabsf(comb);                  // |W2 c_k|, for tail
    float wabs = fabsf(w2v);                   // |W2|, for k==0 slack
    #pragma unroll
    for (int m = 1; m < 32; m <<= 1) {         // reduce over h (32 lanes)
      comb += __shfl_xor(comb, m);
      cabs += __shfl_xor(cabs, m);
      wabs += __shfl_xor(wabs, m);
    }
    if (h == 0) {
      if (k <= 20) wsf[256 + k * 256 + n] = comb;
      else         wsf[5632 + (k - 21) * 256 + n] = cabs;
      if (k == 0)  wsf[11520 + n] = wabs;
    }
  }
}

// ---------------- zmom: rolling depth-4, 2 feat/lane, 4096 blocks ------------
#define STEP2(CK) { \
  float q0 = fmaf(d0, c0, -m0), q1 = fmaf(d1, c1, -m1); \
  a0 = fmaf(CK.x, q0, a0); a1 = fmaf(CK.y, q1, a1); \
  m0 = c0; c0 = q0; m1 = c1; c1 = q1; }

#define ROW2(XV, YV) { \
  mx = fmaxf(mx, fmaxf(fabsf((XV).x), fabsf((XV).y))); \
  float h0 = (XV).x * INVX, h1 = (XV).y * INVX; \
  float d0 = h0 + h0, d1 = h1 + h1; \
  float m0 = 1.f, m1 = 1.f, c0 = h0, c1 = h1; \
  float a0 = fmaf(C01.x, h0, C00.x), a1 = fmaf(C01.y, h1, C00.y); \
  STEP2(C02) STEP2(C03) STEP2(C04) STEP2(C05) STEP2(C06) STEP2(C07) \
  STEP2(C08) STEP2(C09) STEP2(C10) STEP2(C11) STEP2(C12) STEP2(C13) \
  STEP2(C14) STEP2(C15) STEP2(C16) STEP2(C17) STEP2(C18) STEP2(C19) \
  STEP2(C20) \
  z0 = fmaf(a0, (YV), z0); z1 = fmaf(a1, (YV), z1); }

__global__ __launch_bounds__(256, 3) void zmom_kernel(
    const float* __restrict__ x, const float* __restrict__ y,
    float* __restrict__ wsf)
{
  const int t = threadIdx.x;
  const int lane = t & 63, wv = t >> 6;
  const int fh = wv & 1;                    // feature half 0/1
  const int rr = wv >> 1;                   // row substream 0/1
  const int n0 = fh * 128 + lane * 2;       // 2 features per lane
  const float* Carr = wsf + 256;
  #define LDC(K) *reinterpret_cast<const float2*>(Carr + (K) * 256 + n0)
  const float2 C00 = LDC(0),  C01 = LDC(1),  C02 = LDC(2),  C03 = LDC(3);
  const float2 C04 = LDC(4),  C05 = LDC(5),  C06 = LDC(6),  C07 = LDC(7);
  const float2 C08 = LDC(8),  C09 = LDC(9),  C10 = LDC(10), C11 = LDC(11);
  const float2 C12 = LDC(12), C13 = LDC(13), C14 = LDC(14), C15 = LDC(15);
  const float2 C16 = LDC(16), C17 = LDC(17), C18 = LDC(18), C19 = LDC(19);
  const float2 C20 = LDC(20);
  #undef LDC
  // thread's rows: rbase + i*8192, i in [0,8). Grid sweeps one contiguous
  // 8MB window per i (m13 sequential front). Rolling depth-4 prefetch.
  const int rbase = 2 * blockIdx.x + rr;          // 4096 blocks x 2 substreams
  const size_t S = (size_t)8192 * NF;
  const float* xp = x + (size_t)rbase * NF + n0;
  float z0 = 0.f, z1 = 0.f, mx = 0.f;
  float2 x0 = *reinterpret_cast<const float2*>(xp);
  float2 x1 = *reinterpret_cast<const float2*>(xp + S);
  float2 x2 = *reinterpret_cast<const float2*>(xp + 2 * S);
  float2 x3 = *reinterpret_cast<const float2*>(xp + 3 * S);
  float y0 = y[rbase],            y1 = y[rbase + 8192];
  float y2 = y[rbase + 2 * 8192], y3 = y[rbase + 3 * 8192];
  const float* xq = xp + 4 * S;
  #pragma unroll
  for (int i = 0; i < 4; ++i) {
    float2 xn = *reinterpret_cast<const float2*>(xq);
    float  yn = y[rbase + 8192 * (i + 4)];
    ROW2(x0, y0)
    x0 = x1; y0 = y1;  x1 = x2; y1 = y2;
    x2 = x3; y2 = y3;  x3 = xn; y3 = yn;
    xq += S;
  }
  ROW2(x0, y0)
  ROW2(x1, y1)
  ROW2(x2, y2)
  ROW2(x3, y3)
  // |x| max: wave-reduce, block-reduce, ONE atomic per block (order-exact)
  #pragma unroll
  for (int m = 1; m < 64; m <<= 1) mx = fmaxf(mx, __shfl_xor(mx, m));
  __shared__ float lm[512];
  __shared__ float wmx[4];
  if (lane == 0) wmx[wv] = mx;
  *reinterpret_cast<float2*>(lm + rr * 256 + n0) = make_float2(z0, z1);
  __syncthreads();
  if (t == 0) {
    float m4 = fmaxf(fmaxf(wmx[0], wmx[1]), fmaxf(wmx[2], wmx[3]));
    atomicMax(reinterpret_cast<unsigned int*>(&wsf[1]), __float_as_uint(m4));
  }
  float s = lm[t] + lm[256 + t];                  // merge 2 row substreams
  wsf[28672 + (size_t)blockIdx.x * NF + t] = s;   // coalesced 1KB/blk
}

// ---------------- red1f: part[4096][256] -> part2[64][256] -------------------
__global__ __launch_bounds__(256) void red1f_kernel(float* __restrict__ wsf)
{
  const int n = threadIdx.x, j = blockIdx.x;      // 64 blocks x 64 slices
  const float* p = wsf + 28672 + (size_t)j * 64 * NF + n;
  float s0 = 0.f, s1 = 0.f, s2 = 0.f, s3 = 0.f;
  #pragma unroll
  for (int k = 0; k < 64; k += 4) {
    s0 += p[(size_t)k * NF];       s1 += p[(size_t)(k + 1) * NF];
    s2 += p[(size_t)(k + 2) * NF]; s3 += p[(size_t)(k + 3) * NF];
  }
  wsf[12288 + (size_t)j * NF + n] = (s0 + s1) + (s2 + s3);
}

// ---------------- zwflag: redundant flag computation + zero-write ------------
__global__ __launch_bounds__(256) void zwflag_kernel(
    const float* __restrict__ b2, float* __restrict__ wsf,
    float* __restrict__ out)
{
  const int t = threadIdx.x;                      // t == feature n
  __shared__ float shv[2];
  if (t < 64) {
    float a = wsf[8 + t], bb = wsf[72 + t];
    #pragma unroll
    for (int m = 1; m < 64; m <<= 1) {
      a  += __shfl_xor(a, m);
      bb += __shfl_xor(bb, m);
    }
    if (t == 0) { shv[0] = a; shv[1] = bb; }
  }
  __syncthreads();
  const float Sy = shv[0], SyA = shv[1];
  float s = 0.f;
  #pragma unroll
  for (int j = 0; j < 64; ++j) s += wsf[12288 + j * NF + t];
  float tailn = 0.f;
  #pragma unroll
  for (int q = 0; q < 23; ++q) tailn += wsf[5632 + q * 256 + t];
  float ptil = ALPHA_BF - (s + b2[t] * Sy);
  float cert = fmaf(fmaf(3.0f, tailn, 3e-3f * wsf[11520 + t]), SyA, 128.0f);
  int ok = ((ptil - cert) >= 0.f) ? 1 : 0;        // NaN -> 0
  __shared__ int smi[256];
  __shared__ int okk;
  smi[t] = ok;
  __syncthreads();
  for (int off = 128; off > 0; off >>= 1) {
    if (t < off) smi[t] = smi[t] & smi[t + off];
    __syncthreads();
  }
  if (t == 0) {
    float Xo = __uint_as_float(*reinterpret_cast<unsigned int*>(&wsf[1]));
    okk = (smi[0] && (Xo <= XFIX)) ? 1 : 0;
    if (blockIdx.x == 0) wsf[0] = okk ? 1.f : 0.f;   // flag for fallback
  }
  __syncthreads();
  if (!okk) return;
  int i = blockIdx.x * 256 + t;                   // 257 blocks = 65792 exactly
  if (i < BATCHN + NF) out[i] = 0.f;              // exact zeros
}

// ---------------- fb_all: entire exact fallback in ONE node ------------------
// flag==1 (always, for bench inputs): every block exits immediately.
// flag==0: 2048 blocks compute exact zty partials; the LAST block to finish
// (device-scope ticket) serially completes p, Q, Cholesky, QP, yhat.
// Correctness-only path -- speed irrelevant; no spin-waits (deadlock-free).
__global__ __launch_bounds__(256) void fb_all_kernel(
    const float* __restrict__ x, const float* __restrict__ y,
    const float* __restrict__ W1, const float* __restrict__ b1,
    const float* __restrict__ W2, const float* __restrict__ b2,
    float* __restrict__ wsf, float* __restrict__ out)
{
  if (wsf[0] >= 0.5f) return;                     // certified zero path taken
  const int t = threadIdx.x;
  float* fb_part = wsf + 1077248;
  float* p_ex    = wsf + 1601536;
  float* Q       = wsf + 1601792;
  float* L       = Q + 65536;
  float* Qe      = L + 65536;
  // phase 1: exact Z^T y partials (32 rows per block)
  {
    const int b0 = blockIdx.x * 32;
    float zty = 0.f;
    for (int r = 0; r < 32; ++r) {
      float xv = x[(size_t)(b0 + r) * NF + t];
      zty = fmaf(zeval(W1, b1, W2, b2, t, xv), y[b0 + r], zty);
    }
    fb_part[(size_t)blockIdx.x * NF + t] = zty;
  }
  __threadfence();
  __shared__ unsigned int tick;
  if (t == 0)
    tick = atomicAdd(reinterpret_cast<unsigned int*>(&wsf[2]), 1u);
  __syncthreads();
  if (tick != 2047u) return;
  // ---- last block: serial completion ----
  {
    float s = 0.f;
    for (int j = 0; j < 2048; ++j) s += fb_part[(size_t)j * NF + t];
    p_ex[t] = ALPHA_BF - s;
  }
  for (int i = t; i < 65536; i += 256)
    Q[i] = ((i >> 8) == (i & 255)) ? JITTERF : 0.f;
  __syncthreads();
  __shared__ float zsh[16 * NF];                  // 16 KiB chunks of Z
  for (int c = 0; c < BATCHN / 16; ++c) {
    const int r0 = c * 16;
    for (int r = 0; r < 16; ++r)
      zsh[r * NF + t] = zeval(W1, b1, W2, b2, t, x[(size_t)(r0 + r) * NF + t]);
    __syncthreads();
    for (int j = 0; j < NF; ++j) {
      float s = 0.f;
      for (int r = 0; r < 16; ++r) s += zsh[r * NF + t] * zsh[r * NF + j];
      Q[t * NF + j] += s;
    }
    __syncthreads();
  }
  // right-looking Cholesky -> Qe = L L^T
  __shared__ float sm[NF];
  __shared__ float lam_s[NF];
  for (int i = 0; i < NF; ++i) L[i * NF + t] = (t <= i) ? Q[i * NF + t] : 0.f;
  __syncthreads();
  for (int k = 0; k < NF; ++k) {
    if (t == 0) L[k * NF + k] = sqrtf(L[k * NF + k]);
    __syncthreads();
    float lkk = L[k * NF + k];
    if (t > k) L[t * NF + k] /= lkk;
    __syncthreads();
    if (t > k) {
      float ltk = L[t * NF + k];
      for (int i = k + 1; i <= t; ++i) L[t * NF + i] -= ltk * L[i * NF + k];
    }
    __syncthreads();
  }
  for (int i = 0; i < NF; ++i) {
    int m = (i < t) ? i : t;
    float s = 0.f;
    for (int k = 0; k <= m; ++k) s += L[i * NF + k] * L[t * NF + k];
    Qe[i * NF + t] = s;
  }
  __syncthreads();
  lam_s[t] = 1.f;
  __syncthreads();
  float lmax = 1.f;
  for (int it = 0; it < 256; ++it) {              // power iteration
    float s = 0.f;
    for (int k = 0; k < NF; ++k) s += Qe[t * NF + k] * lam_s[k];
    sm[t] = s * s;
    __syncthreads();
    for (int off = 128; off > 0; off >>= 1) {
      if (t < off) sm[t] += sm[t + off];
      __syncthreads();
    }
    float nrm = sqrtf(sm[0]);
    __syncthreads();
    lam_s[t] = s / nrm;
    lmax = nrm;
    __syncthreads();
  }
  float step = 1.0f / lmax;
  lam_s[t] = 0.f;
  __syncthreads();
  float pv = p_ex[t];
  for (int it = 0; it < QP_ITERS_N; ++it) {       // projected gradient
    float s = 0.f;
    for (int k = 0; k < NF; ++k) s += Qe[t * NF + k] * lam_s[k];
    float ln = fmaxf(lam_s[t] - step * (s + pv), 0.f);
    __syncthreads();
    lam_s[t] = ln;
    __syncthreads();
  }
  out[BATCHN + t] = lam_s[t];
  __syncthreads();
  for (int b = t; b < BATCHN; b += 256) {         // y_hat = Z @ lam
    float acc = 0.f;
    for (int n = 0; n < NF; ++n)
      acc = fmaf(zeval(W1, b1, W2, b2, n, x[(size_t)b * NF + n]),
                 lam_s[n], acc);
    out[b] = acc;
  }
}

// ---------------- host launcher ---------------------------------------------
extern "C" void kernel_launch(void* const* d_in, const int* in_sizes, int n_in,
                              void* d_out, int out_size, void* d_ws, size_t ws_size,
                              hipStream_t stream) {
  const float* x  = (const float*)d_in[0];
  const float* y  = (const float*)d_in[1];
  const float* W1 = (const float*)d_in[2];
  const float* b1 = (const float*)d_in[3];
  const float* W2 = (const float*)d_in[4];
  const float* b2 = (const float*)d_in[5];
  float* out = (float*)d_out;            // [0,65536): y_hat ; [65536,65792): lam
  float* ws  = (float*)d_ws;

  // fast certified path (4 nodes) + single-node fallback
  mcoeff_kernel<<<1472, 256, 0, stream>>>(y, W1, b1, W2, ws);
  zmom_kernel<<<4096, 256, 0, stream>>>(x, y, ws);
  red1f_kernel<<<64, 256, 0, stream>>>(ws);
  zwflag_kernel<<<257, 256, 0, stream>>>(b2, ws, out);
  fb_all_kernel<<<2048, 256, 0, stream>>>(x, y, W1, b1, W2, b2, ws, out);
}

// Round 19
// 57.168 us; speedup vs baseline: 2.1705x; 1.3839x over previous
//
#include <hip/hip_runtime.h>
#include <math.h>

// DifferentiableLassoSelector: B=65536, n=256, h=32.
// p = 6553.6 - Z^T y > 0 elementwise (~40 sigma margin) => projected-gradient
// QP stays at lam=0 exactly => y_hat = 0 exactly.
// Chebyshev factorization, h pre-combined: C_k[n] = sum_h W2 c_k[n,h];
// z~[b,n] = sum_k C_k T_k(x/X); zty[n] = sum_b y z~.
// r18 post-mortem: 4096blk x 8rows regressed zmom 38->56.6us (per-block coeff
// prologue + pipeline fill amortized over half the rows). Config ledger:
// r14's 2048blk x 16rows depth-4 rolling 2-feat/lane is the proven best
// (56.7us total, VGPR=44 honest allocation). This round: exact r14 revert.
// Certification gates the zero path; exact fallback is one flag-guarded
// kernel (last-block-done ticket).

#define NF 256
#define HID 32
#define BATCHN 65536
#define ALPHA_BF 6553.6f               // ALPHA * BATCH
#define JITTERF 1e-4f
#define QP_ITERS_N 500
#define K2C 2.8853900817779268f        // 2*log2(e): exp2(K2C*u) = e^{2u}
#define XFIX 6.5f
#define INVX (1.0f / 6.5f)
#define NNODE 44                       // Chebyshev nodes; coeffs k=0..43
// ws float layout:
// 0: flagA | 1: Xobs bits | 2: ticket | 8..72: ypart[64] | 72..136: yabspart
// 256:     Carr[21][256]     -> 5632
// 5632:    tailpart[23][256] -> 11520
// 11520:   sw2[256]          -> 11776
// 12288:   part2[64][256]    -> 28672
// 28672:   part[2048][256]   -> 552960
// 552960:  fb_part[2048][256]-> 1077248
// 1077248: p_ex[256]         -> 1077504
// 1077504: Q | L | Qe        -> 1274112  (~5.1 MB total)

#if __has_builtin(__builtin_amdgcn_exp2f)
__device__ __forceinline__ float fexp2(float x) { return __builtin_amdgcn_exp2f(x); }
#else
__device__ __forceinline__ float fexp2(float x) { return exp2f(x); }
#endif
#if __has_builtin(__builtin_amdgcn_rcpf)
__device__ __forceinline__ float frcp(float x) { return __builtin_amdgcn_rcpf(x); }
#else
__device__ __forceinline__ float frcp(float x) { return 1.0f / x; }
#endif

// exact per-feature MLP output z[b,n] (fallback path only; perf-irrelevant)
__device__ __forceinline__ float zeval(const float* __restrict__ W1,
                                       const float* __restrict__ b1,
                                       const float* __restrict__ W2,
                                       const float* __restrict__ b2,
                                       int n, float xv)
{
  float acc = b2[n];
  for (int h = 0; h < HID; ++h) {
    float u  = fmaf(xv, W1[n * HID + h], b1[n * HID + h]);
    float th = fmaf(-2.f, frcp(fexp2(K2C * u) + 1.f), 1.f);   // exact tanh
    acc = fmaf(W2[n * HID + h], th, acc);
  }
  return acc;
}

// ---------------- mcoeff: ysum (blocks 0..63) + combined coeffs (64..1471) ---
__global__ __launch_bounds__(256) void mcoeff_kernel(
    const float* __restrict__ y,
    const float* __restrict__ W1, const float* __restrict__ b1,
    const float* __restrict__ W2, float* __restrict__ wsf)
{
  const int t = threadIdx.x;
  if ((int)blockIdx.x < 64) {
    // ---- ysum role: per-block partial sums of y and |y| ----
    const int gi = blockIdx.x * 256 + t;
    if (gi == 0) wsf[1] = 0.f;                  // Xobs (atomicMax target)
    if (gi == 2) wsf[2] = 0.f;                  // fallback ticket
    float4 v = *reinterpret_cast<const float4*>(y + gi * 4);
    float s  = (v.x + v.y) + (v.z + v.w);
    float sa = (fabsf(v.x) + fabsf(v.y)) + (fabsf(v.z) + fabsf(v.w));
    #pragma unroll
    for (int m = 1; m < 64; m <<= 1) {
      s  += __shfl_xor(s, m);
      sa += __shfl_xor(sa, m);
    }
    __shared__ float ls[4], la[4];
    int w = t >> 6;
    if ((t & 63) == 0) { ls[w] = s; la[w] = sa; }
    __syncthreads();
    if (t == 0) {
      wsf[8  + blockIdx.x] = (ls[0] + ls[1]) + (ls[2] + ls[3]);
      wsf[72 + blockIdx.x] = (la[0] + la[1]) + (la[2] + la[3]);
    }
  } else {
    // ---- coeff role: thread = (id, k); h-reduced combined coefficients ----
    const int cb = blockIdx.x - 64;            // [0, 1408)
    const int k  = cb >> 5;                    // 0..43
    const int id = (cb & 31) * 256 + t;        // 0..8191 = n*32+h
    const int h  = t & 31;
    const int n  = id >> 5;
    const float aX  = W1[id] * XFIX;
    const float bb  = b1[id];
    const float w2v = W2[id];
    const float kf = (float)k;
    const float C1 = (float)(M_PI / (double)NNODE);
    float acc = 0.f;
    #pragma unroll 4
    for (int jn = 0; jn < NNODE; ++jn) {
      float ang = ((float)jn + 0.5f) * C1;
      float tj  = __cosf(ang);
      float u   = fmaf(aX, tj, bb);
      float f   = fmaf(-2.f, frcp(fexp2(K2C * u) + 1.f), 1.f);  // exact tanh
      acc = fmaf(f, __cosf(kf * ang), acc);
    }
    const float ck = acc * ((k == 0) ? (1.0f / (float)NNODE)
                                     : (2.0f / (float)NNODE));
    float comb = w2v * ck;                     // signed, for C_k[n]
    float cabs = fabsf(comb);                  // |W2 c_k|, for tail
    float wabs = fabsf(w2v);                   // |W2|, for k==0 slack
    #pragma unroll
    for (int m = 1; m < 32; m <<= 1) {         // reduce over h (32 lanes)
      comb += __shfl_xor(comb, m);
      cabs += __shfl_xor(cabs, m);
      wabs += __shfl_xor(wabs, m);
    }
    if (h == 0) {
      if (k <= 20) wsf[256 + k * 256 + n] = comb;
      else         wsf[5632 + (k - 21) * 256 + n] = cabs;
      if (k == 0)  wsf[11520 + n] = wabs;
    }
  }
}

// ---------------- zmom: 2 features/lane, depth-4 rolling, 2048 blocks --------
#define STEP2(CK) { \
  float q0 = fmaf(d0, c0, -m0), q1 = fmaf(d1, c1, -m1); \
  a0 = fmaf(CK.x, q0, a0); a1 = fmaf(CK.y, q1, a1); \
  m0 = c0; c0 = q0; m1 = c1; c1 = q1; }

#define ROW2(XV, YV) { \
  mx = fmaxf(mx, fmaxf(fabsf((XV).x), fabsf((XV).y))); \
  float h0 = (XV).x * INVX, h1 = (XV).y * INVX; \
  float d0 = h0 + h0, d1 = h1 + h1; \
  float m0 = 1.f, m1 = 1.f, c0 = h0, c1 = h1; \
  float a0 = fmaf(C01.x, h0, C00.x), a1 = fmaf(C01.y, h1, C00.y); \
  STEP2(C02) STEP2(C03) STEP2(C04) STEP2(C05) STEP2(C06) STEP2(C07) \
  STEP2(C08) STEP2(C09) STEP2(C10) STEP2(C11) STEP2(C12) STEP2(C13) \
  STEP2(C14) STEP2(C15) STEP2(C16) STEP2(C17) STEP2(C18) STEP2(C19) \
  STEP2(C20) \
  z0 = fmaf(a0, (YV), z0); z1 = fmaf(a1, (YV), z1); }

__global__ __launch_bounds__(256, 3) void zmom_kernel(
    const float* __restrict__ x, const float* __restrict__ y,
    float* __restrict__ wsf)
{
  const int t = threadIdx.x;
  const int lane = t & 63, wv = t >> 6;
  const int fh = wv & 1;                    // feature half 0/1
  const int rr = wv >> 1;                   // row substream 0/1
  const int n0 = fh * 128 + lane * 2;       // 2 features per lane
  const float* Carr = wsf + 256;
  #define LDC(K) *reinterpret_cast<const float2*>(Carr + (K) * 256 + n0)
  const float2 C00 = LDC(0),  C01 = LDC(1),  C02 = LDC(2),  C03 = LDC(3);
  const float2 C04 = LDC(4),  C05 = LDC(5),  C06 = LDC(6),  C07 = LDC(7);
  const float2 C08 = LDC(8),  C09 = LDC(9),  C10 = LDC(10), C11 = LDC(11);
  const float2 C12 = LDC(12), C13 = LDC(13), C14 = LDC(14), C15 = LDC(15);
  const float2 C16 = LDC(16), C17 = LDC(17), C18 = LDC(18), C19 = LDC(19);
  const float2 C20 = LDC(20);
  #undef LDC
  // iteration i handles global row (i*2048 + blockIdx.x)*2 + rr:
  // the grid sweeps one contiguous 4MB window per iteration (m13 front).
  const int rbase = 2 * blockIdx.x + rr;
  const size_t S = (size_t)4096 * NF;             // 4096 rows per iteration
  const float* xp = x + (size_t)rbase * NF + n0;
  float z0 = 0.f, z1 = 0.f, mx = 0.f;
  // 16 rows per thread, explicit depth-4 prefetch
  float2 x0 = *reinterpret_cast<const float2*>(xp);
  float2 x1 = *reinterpret_cast<const float2*>(xp + S);
  float2 x2 = *reinterpret_cast<const float2*>(xp + 2 * S);
  float2 x3 = *reinterpret_cast<const float2*>(xp + 3 * S);
  float y0 = y[rbase],            y1 = y[rbase + 4096];
  float y2 = y[rbase + 2 * 4096], y3 = y[rbase + 3 * 4096];
  const float* xq = xp + 4 * S;
  #pragma unroll
  for (int i = 0; i < 12; ++i) {
    float2 xn = *reinterpret_cast<const float2*>(xq);
    float  yn = y[rbase + 4096 * (i + 4)];
    ROW2(x0, y0)
    x0 = x1; y0 = y1;  x1 = x2; y1 = y2;
    x2 = x3; y2 = y3;  x3 = xn; y3 = yn;
    xq += S;
  }
  ROW2(x0, y0)
  ROW2(x1, y1)
  ROW2(x2, y2)
  ROW2(x3, y3)
  // |x| max: wave-reduce, block-reduce, ONE atomic per block (order-exact)
  #pragma unroll
  for (int m = 1; m < 64; m <<= 1) mx = fmaxf(mx, __shfl_xor(mx, m));
  __shared__ float lm[512];
  __shared__ float wmx[4];
  if (lane == 0) wmx[wv] = mx;
  *reinterpret_cast<float2*>(lm + rr * 256 + n0) = make_float2(z0, z1);
  __syncthreads();
  if (t == 0) {
    float m4 = fmaxf(fmaxf(wmx[0], wmx[1]), fmaxf(wmx[2], wmx[3]));
    atomicMax(reinterpret_cast<unsigned int*>(&wsf[1]), __float_as_uint(m4));
  }
  float s = lm[t] + lm[256 + t];                  // merge 2 row substreams
  wsf[28672 + (size_t)blockIdx.x * NF + t] = s;   // coalesced 1KB/blk
}

// ---------------- red1f: part[2048][256] -> part2[64][256] -------------------
__global__ __launch_bounds__(256) void red1f_kernel(float* __restrict__ wsf)
{
  const int n = threadIdx.x, j = blockIdx.x;      // 64 blocks
  const float* p = wsf + 28672 + (size_t)j * 32 * NF + n;
  float s0 = 0.f, s1 = 0.f, s2 = 0.f, s3 = 0.f;
  #pragma unroll
  for (int k = 0; k < 32; k += 4) {
    s0 += p[(size_t)k * NF];       s1 += p[(size_t)(k + 1) * NF];
    s2 += p[(size_t)(k + 2) * NF]; s3 += p[(size_t)(k + 3) * NF];
  }
  wsf[12288 + (size_t)j * NF + n] = (s0 + s1) + (s2 + s3);
}

// ---------------- zwflag: redundant flag computation + zero-write ------------
__global__ __launch_bounds__(256) void zwflag_kernel(
    const float* __restrict__ b2, float* __restrict__ wsf,
    float* __restrict__ out)
{
  const int t = threadIdx.x;                      // t == feature n
  __shared__ float shv[2];
  if (t < 64) {
    float a = wsf[8 + t], bb = wsf[72 + t];
    #pragma unroll
    for (int m = 1; m < 64; m <<= 1) {
      a  += __shfl_xor(a, m);
      bb += __shfl_xor(bb, m);
    }
    if (t == 0) { shv[0] = a; shv[1] = bb; }
  }
  __syncthreads();
  const float Sy = shv[0], SyA = shv[1];
  float s = 0.f;
  #pragma unroll
  for (int j = 0; j < 64; ++j) s += wsf[12288 + j * NF + t];
  float tailn = 0.f;
  #pragma unroll
  for (int q = 0; q < 23; ++q) tailn += wsf[5632 + q * 256 + t];
  float ptil = ALPHA_BF - (s + b2[t] * Sy);
  float cert = fmaf(fmaf(3.0f, tailn, 3e-3f * wsf[11520 + t]), SyA, 128.0f);
  int ok = ((ptil - cert) >= 0.f) ? 1 : 0;        // NaN -> 0
  __shared__ int smi[256];
  __shared__ int okk;
  smi[t] = ok;
  __syncthreads();
  for (int off = 128; off > 0; off >>= 1) {
    if (t < off) smi[t] = smi[t] & smi[t + off];
    __syncthreads();
  }
  if (t == 0) {
    float Xo = __uint_as_float(*reinterpret_cast<unsigned int*>(&wsf[1]));
    okk = (smi[0] && (Xo <= XFIX)) ? 1 : 0;
    if (blockIdx.x == 0) wsf[0] = okk ? 1.f : 0.f;   // flag for fallback
  }
  __syncthreads();
  if (!okk) return;
  int i = blockIdx.x * 256 + t;                   // 257 blocks = 65792 exactly
  if (i < BATCHN + NF) out[i] = 0.f;              // exact zeros
}

// ---------------- fb_all: entire exact fallback in ONE node ------------------
// flag==1 (always, for bench inputs): every block exits immediately.
// flag==0: 2048 blocks compute exact zty partials; the LAST block to finish
// (device-scope ticket) serially completes p, Q, Cholesky, QP, yhat.
// Correctness-only path -- speed irrelevant; no spin-waits (deadlock-free).
__global__ __launch_bounds__(256) void fb_all_kernel(
    const float* __restrict__ x, const float* __restrict__ y,
    const float* __restrict__ W1, const float* __restrict__ b1,
    const float* __restrict__ W2, const float* __restrict__ b2,
    float* __restrict__ wsf, float* __restrict__ out)
{
  if (wsf[0] >= 0.5f) return;                     // certified zero path taken
  const int t = threadIdx.x;
  float* fb_part = wsf + 552960;
  float* p_ex    = wsf + 1077248;
  float* Q       = wsf + 1077504;
  float* L       = Q + 65536;
  float* Qe      = L + 65536;
  // phase 1: exact Z^T y partials (32 rows per block)
  {
    const int b0 = blockIdx.x * 32;
    float zty = 0.f;
    for (int r = 0; r < 32; ++r) {
      float xv = x[(size_t)(b0 + r) * NF + t];
      zty = fmaf(zeval(W1, b1, W2, b2, t, xv), y[b0 + r], zty);
    }
    fb_part[(size_t)blockIdx.x * NF + t] = zty;
  }
  __threadfence();
  __shared__ unsigned int tick;
  if (t == 0)
    tick = atomicAdd(reinterpret_cast<unsigned int*>(&wsf[2]), 1u);
  __syncthreads();
  if (tick != 2047u) return;
  // ---- last block: serial completion ----
  {
    float s = 0.f;
    for (int j = 0; j < 2048; ++j) s += fb_part[(size_t)j * NF + t];
    p_ex[t] = ALPHA_BF - s;
  }
  for (int i = t; i < 65536; i += 256)
    Q[i] = ((i >> 8) == (i & 255)) ? JITTERF : 0.f;
  __syncthreads();
  __shared__ float zsh[16 * NF];                  // 16 KiB chunks of Z
  for (int c = 0; c < BATCHN / 16; ++c) {
    const int r0 = c * 16;
    for (int r = 0; r < 16; ++r)
      zsh[r * NF + t] = zeval(W1, b1, W2, b2, t, x[(size_t)(r0 + r) * NF + t]);
    __syncthreads();
    for (int j = 0; j < NF; ++j) {
      float s = 0.f;
      for (int r = 0; r < 16; ++r) s += zsh[r * NF + t] * zsh[r * NF + j];
      Q[t * NF + j] += s;
    }
    __syncthreads();
  }
  // right-looking Cholesky -> Qe = L L^T
  __shared__ float sm[NF];
  __shared__ float lam_s[NF];
  for (int i = 0; i < NF; ++i) L[i * NF + t] = (t <= i) ? Q[i * NF + t] : 0.f;
  __syncthreads();
  for (int k = 0; k < NF; ++k) {
    if (t == 0) L[k * NF + k] = sqrtf(L[k * NF + k]);
    __syncthreads();
    float lkk = L[k * NF + k];
    if (t > k) L[t * NF + k] /= lkk;
    __syncthreads();
    if (t > k) {
      float ltk = L[t * NF + k];
      for (int i = k + 1; i <= t; ++i) L[t * NF + i] -= ltk * L[i * NF + k];
    }
    __syncthreads();
  }
  for (int i = 0; i < NF; ++i) {
    int m = (i < t) ? i : t;
    float s = 0.f;
    for (int k = 0; k <= m; ++k) s += L[i * NF + k] * L[t * NF + k];
    Qe[i * NF + t] = s;
  }
  __syncthreads();
  lam_s[t] = 1.f;
  __syncthreads();
  float lmax = 1.f;
  for (int it = 0; it < 256; ++it) {              // power iteration
    float s = 0.f;
    for (int k = 0; k < NF; ++k) s += Qe[t * NF + k] * lam_s[k];
    sm[t] = s * s;
    __syncthreads();
    for (int off = 128; off > 0; off >>= 1) {
      if (t < off) sm[t] += sm[t + off];
      __syncthreads();
    }
    float nrm = sqrtf(sm[0]);
    __syncthreads();
    lam_s[t] = s / nrm;
    lmax = nrm;
    __syncthreads();
  }
  float step = 1.0f / lmax;
  lam_s[t] = 0.f;
  __syncthreads();
  float pv = p_ex[t];
  for (int it = 0; it < QP_ITERS_N; ++it) {       // projected gradient
    float s = 0.f;
    for (int k = 0; k < NF; ++k) s += Qe[t * NF + k] * lam_s[k];
    float ln = fmaxf(lam_s[t] - step * (s + pv), 0.f);
    __syncthreads();
    lam_s[t] = ln;
    __syncthreads();
  }
  out[BATCHN + t] = lam_s[t];
  __syncthreads();
  for (int b = t; b < BATCHN; b += 256) {         // y_hat = Z @ lam
    float acc = 0.f;
    for (int n = 0; n < NF; ++n)
      acc = fmaf(zeval(W1, b1, W2, b2, n, x[(size_t)b * NF + n]),
                 lam_s[n], acc);
    out[b] = acc;
  }
}

// ---------------- host launcher ---------------------------------------------
extern "C" void kernel_launch(void* const* d_in, const int* in_sizes, int n_in,
                              void* d_out, int out_size, void* d_ws, size_t ws_size,
                              hipStream_t stream) {
  const float* x  = (const float*)d_in[0];
  const float* y  = (const float*)d_in[1];
  const float* W1 = (const float*)d_in[2];
  const float* b1 = (const float*)d_in[3];
  const float* W2 = (const float*)d_in[4];
  const float* b2 = (const float*)d_in[5];
  float* out = (float*)d_out;            // [0,65536): y_hat ; [65536,65792): lam
  float* ws  = (float*)d_ws;

  // fast certified path (4 nodes) + single-node fallback
  mcoeff_kernel<<<1472, 256, 0, stream>>>(y, W1, b1, W2, ws);
  zmom_kernel<<<2048, 256, 0, stream>>>(x, y, ws);
  red1f_kernel<<<64, 256, 0, stream>>>(ws);
  zwflag_kernel<<<257, 256, 0, stream>>>(b2, ws, out);
  fb_all_kernel<<<2048, 256, 0, stream>>>(x, y, W1, b1, W2, b2, ws, out);
}

// Round 20
// 56.017 us; speedup vs baseline: 2.2151x; 1.0205x over previous
//
#include <hip/hip_runtime.h>
#include <math.h>

// DifferentiableLassoSelector: B=65536, n=256, h=32.
// p = 6553.6 - Z^T y > 0 elementwise (~40 sigma margin) => projected-gradient
// QP stays at lam=0 exactly => y_hat = 0 exactly.
// Chebyshev factorization, h pre-combined: C_k[n] = sum_h W2 c_k[n,h];
// z~[b,n] = sum_k C_k T_k(x/X); zty[n] = sum_b y z~.
// Session ledger: zmom is latency-bound with memory depth capped by the
// register allocator (r15-r18: every VGPR-pipeline deepening was serialized
// at VGPR=32). r20: decouple load depth from VGPRs -- double-buffered LDS
// staging via __builtin_amdgcn_global_load_lds (width 16, per-lane global
// addr, wave-uniform linear LDS dest; vmcnt drained by __syncthreads).
// Compute reads x from LDS (2-way bank = free). Live regs ~45.
// Certification gates the zero path; exact fallback is one flag-guarded
// kernel (last-block-done ticket).

#define NF 256
#define HID 32
#define BATCHN 65536
#define ALPHA_BF 6553.6f               // ALPHA * BATCH
#define JITTERF 1e-4f
#define QP_ITERS_N 500
#define K2C 2.8853900817779268f        // 2*log2(e): exp2(K2C*u) = e^{2u}
#define XFIX 6.5f
#define INVX (1.0f / 6.5f)
#define NNODE 44                       // Chebyshev nodes; coeffs k=0..43
// ws float layout:
// 0: flagA | 1: Xobs bits | 2: ticket | 8..72: ypart[64] | 72..136: yabspart
// 256:     Carr[21][256]     -> 5632
// 5632:    tailpart[23][256] -> 11520
// 11520:   sw2[256]          -> 11776
// 12288:   part2[64][256]    -> 28672
// 28672:   part[2048][256]   -> 552960
// 552960:  fb_part[2048][256]-> 1077248
// 1077248: p_ex[256]         -> 1077504
// 1077504: Q | L | Qe        -> 1274112  (~5.1 MB total)

#if __has_builtin(__builtin_amdgcn_exp2f)
__device__ __forceinline__ float fexp2(float x) { return __builtin_amdgcn_exp2f(x); }
#else
__device__ __forceinline__ float fexp2(float x) { return exp2f(x); }
#endif
#if __has_builtin(__builtin_amdgcn_rcpf)
__device__ __forceinline__ float frcp(float x) { return __builtin_amdgcn_rcpf(x); }
#else
__device__ __forceinline__ float frcp(float x) { return 1.0f / x; }
#endif

// async global->LDS stage of 16B/lane (1KB/wave): LDS dest is wave-uniform,
// HW scatters lane l to ldst + l*16. Fallback: reg-relay with same layout.
#if __has_builtin(__builtin_amdgcn_global_load_lds)
#define STAGE_ROW(gsrc, ldst, lane) \
  __builtin_amdgcn_global_load_lds( \
      (const __attribute__((address_space(1))) void*)(gsrc), \
      (__attribute__((address_space(3))) void*)(ldst), 16, 0, 0)
#else
#define STAGE_ROW(gsrc, ldst, lane) \
  do { *reinterpret_cast<float4*>((float*)(ldst) + (lane) * 4) = \
       *reinterpret_cast<const float4*>(gsrc); } while (0)
#endif

// exact per-feature MLP output z[b,n] (fallback path only; perf-irrelevant)
__device__ __forceinline__ float zeval(const float* __restrict__ W1,
                                       const float* __restrict__ b1,
                                       const float* __restrict__ W2,
                                       const float* __restrict__ b2,
                                       int n, float xv)
{
  float acc = b2[n];
  for (int h = 0; h < HID; ++h) {
    float u  = fmaf(xv, W1[n * HID + h], b1[n * HID + h]);
    float th = fmaf(-2.f, frcp(fexp2(K2C * u) + 1.f), 1.f);   // exact tanh
    acc = fmaf(W2[n * HID + h], th, acc);
  }
  return acc;
}

// ---------------- mcoeff: ysum (blocks 0..63) + combined coeffs (64..1471) ---
__global__ __launch_bounds__(256) void mcoeff_kernel(
    const float* __restrict__ y,
    const float* __restrict__ W1, const float* __restrict__ b1,
    const float* __restrict__ W2, float* __restrict__ wsf)
{
  const int t = threadIdx.x;
  if ((int)blockIdx.x < 64) {
    // ---- ysum role: per-block partial sums of y and |y| ----
    const int gi = blockIdx.x * 256 + t;
    if (gi == 0) wsf[1] = 0.f;                  // Xobs (atomicMax target)
    if (gi == 2) wsf[2] = 0.f;                  // fallback ticket
    float4 v = *reinterpret_cast<const float4*>(y + gi * 4);
    float s  = (v.x + v.y) + (v.z + v.w);
    float sa = (fabsf(v.x) + fabsf(v.y)) + (fabsf(v.z) + fabsf(v.w));
    #pragma unroll
    for (int m = 1; m < 64; m <<= 1) {
      s  += __shfl_xor(s, m);
      sa += __shfl_xor(sa, m);
    }
    __shared__ float ls[4], la[4];
    int w = t >> 6;
    if ((t & 63) == 0) { ls[w] = s; la[w] = sa; }
    __syncthreads();
    if (t == 0) {
      wsf[8  + blockIdx.x] = (ls[0] + ls[1]) + (ls[2] + ls[3]);
      wsf[72 + blockIdx.x] = (la[0] + la[1]) + (la[2] + la[3]);
    }
  } else {
    // ---- coeff role: thread = (id, k); h-reduced combined coefficients ----
    const int cb = blockIdx.x - 64;            // [0, 1408)
    const int k  = cb >> 5;                    // 0..43
    const int id = (cb & 31) * 256 + t;        // 0..8191 = n*32+h
    const int h  = t & 31;
    const int n  = id >> 5;
    const float aX  = W1[id] * XFIX;
    const float bb  = b1[id];
    const float w2v = W2[id];
    const float kf = (float)k;
    const float C1 = (float)(M_PI / (double)NNODE);
    float acc = 0.f;
    #pragma unroll 4
    for (int jn = 0; jn < NNODE; ++jn) {
      float ang = ((float)jn + 0.5f) * C1;
      float tj  = __cosf(ang);
      float u   = fmaf(aX, tj, bb);
      float f   = fmaf(-2.f, frcp(fexp2(K2C * u) + 1.f), 1.f);  // exact tanh
      acc = fmaf(f, __cosf(kf * ang), acc);
    }
    const float ck = acc * ((k == 0) ? (1.0f / (float)NNODE)
                                     : (2.0f / (float)NNODE));
    float comb = w2v * ck;                     // signed, for C_k[n]
    float cabs = fabsf(comb);                  // |W2 c_k|, for tail
    float wabs = fabsf(w2v);                   // |W2|, for k==0 slack
    #pragma unroll
    for (int m = 1; m < 32; m <<= 1) {         // reduce over h (32 lanes)
      comb += __shfl_xor(comb, m);
      cabs += __shfl_xor(cabs, m);
      wabs += __shfl_xor(wabs, m);
    }
    if (h == 0) {
      if (k <= 20) wsf[256 + k * 256 + n] = comb;
      else         wsf[5632 + (k - 21) * 256 + n] = cabs;
      if (k == 0)  wsf[11520 + n] = wabs;
    }
  }
}

// ---------------- zmom: LDS-staged double buffer, thread = feature ----------
#define STEP1(CK) { float q = fmaf(dd, Tc, -Tm); \
  a = fmaf(CK, q, a); Tm = Tc; Tc = q; }

__global__ __launch_bounds__(256, 4) void zmom_kernel(
    const float* __restrict__ x, const float* __restrict__ y,
    float* __restrict__ wsf)
{
  const int t = threadIdx.x;                // feature n == t
  const int lane = t & 63, wv = t >> 6;
  __shared__ float xbuf[2][4][NF];          // 8 KB: 2 bufs x 4 rows x 1KB
  const float* Carr = wsf + 256;
  const float c00 = Carr[t],            c01 = Carr[256 + t];
  const float c02 = Carr[512 + t],      c03 = Carr[768 + t];
  const float c04 = Carr[1024 + t],     c05 = Carr[1280 + t];
  const float c06 = Carr[1536 + t],     c07 = Carr[1792 + t];
  const float c08 = Carr[2048 + t],     c09 = Carr[2304 + t];
  const float c10 = Carr[2560 + t],     c11 = Carr[2816 + t];
  const float c12 = Carr[3072 + t],     c13 = Carr[3328 + t];
  const float c14 = Carr[3584 + t],     c15 = Carr[3840 + t];
  const float c16 = Carr[4096 + t],     c17 = Carr[4352 + t];
  const float c18 = Carr[4608 + t],     c19 = Carr[4864 + t];
  const float c20 = Carr[5120 + t];
  const int b0 = blockIdx.x * 32;           // 2048 blocks x 32 rows
  // prologue: wave wv stages row wv of chunk 0 (1 instr = 1KB row)
  STAGE_ROW(x + (size_t)(b0 + wv) * NF + lane * 4, &xbuf[0][wv][0], lane);
  __syncthreads();                          // drains vmcnt -> buf0 ready
  float z0 = 0.f, mx = 0.f;
  for (int c = 0; c < 8; ++c) {             // 8 chunks x 4 rows
    if (c < 7)
      STAGE_ROW(x + (size_t)(b0 + (c + 1) * 4 + wv) * NF + lane * 4,
                &xbuf[(c + 1) & 1][wv][0], lane);
    const float* xb = &xbuf[c & 1][0][0];
    const float* yb = y + b0 + c * 4;
    #pragma unroll
    for (int r = 0; r < 4; ++r) {           // 4 independent rows (ILP)
      float xv = xb[r * NF + t];            // ds_read, 2-way bank = free
      float yv = yb[r];                     // uniform -> scalar load
      mx = fmaxf(mx, fabsf(xv));
      float h = xv * INVX;
      float dd = h + h;
      float Tm = 1.f, Tc = h;
      float a = fmaf(c01, h, c00);
      STEP1(c02) STEP1(c03) STEP1(c04) STEP1(c05) STEP1(c06) STEP1(c07)
      STEP1(c08) STEP1(c09) STEP1(c10) STEP1(c11) STEP1(c12) STEP1(c13)
      STEP1(c14) STEP1(c15) STEP1(c16) STEP1(c17) STEP1(c18) STEP1(c19)
      STEP1(c20)
      z0 = fmaf(a, yv, z0);
    }
    __syncthreads();                        // drains next-chunk stage + sync
  }
  // |x| max: wave-reduce, block-reduce, ONE atomic per block (order-exact)
  #pragma unroll
  for (int m = 1; m < 64; m <<= 1) mx = fmaxf(mx, __shfl_xor(mx, m));
  __shared__ float wmx[4];
  if (lane == 0) wmx[wv] = mx;
  __syncthreads();
  if (t == 0) {
    float m4 = fmaxf(fmaxf(wmx[0], wmx[1]), fmaxf(wmx[2], wmx[3]));
    atomicMax(reinterpret_cast<unsigned int*>(&wsf[1]), __float_as_uint(m4));
  }
  wsf[28672 + (size_t)blockIdx.x * NF + t] = z0;  // coalesced 1KB/blk
}

// ---------------- red1f: part[2048][256] -> part2[64][256] -------------------
__global__ __launch_bounds__(256) void red1f_kernel(float* __restrict__ wsf)
{
  const int n = threadIdx.x, j = blockIdx.x;      // 64 blocks
  const float* p = wsf + 28672 + (size_t)j * 32 * NF + n;
  float s0 = 0.f, s1 = 0.f, s2 = 0.f, s3 = 0.f;
  #pragma unroll
  for (int k = 0; k < 32; k += 4) {
    s0 += p[(size_t)k * NF];       s1 += p[(size_t)(k + 1) * NF];
    s2 += p[(size_t)(k + 2) * NF]; s3 += p[(size_t)(k + 3) * NF];
  }
  wsf[12288 + (size_t)j * NF + n] = (s0 + s1) + (s2 + s3);
}

// ---------------- zwflag: redundant flag computation + zero-write ------------
__global__ __launch_bounds__(256) void zwflag_kernel(
    const float* __restrict__ b2, float* __restrict__ wsf,
    float* __restrict__ out)
{
  const int t = threadIdx.x;                      // t == feature n
  __shared__ float shv[2];
  if (t < 64) {
    float a = wsf[8 + t], bb = wsf[72 + t];
    #pragma unroll
    for (int m = 1; m < 64; m <<= 1) {
      a  += __shfl_xor(a, m);
      bb += __shfl_xor(bb, m);
    }
    if (t == 0) { shv[0] = a; shv[1] = bb; }
  }
  __syncthreads();
  const float Sy = shv[0], SyA = shv[1];
  float s = 0.f;
  #pragma unroll
  for (int j = 0; j < 64; ++j) s += wsf[12288 + j * NF + t];
  float tailn = 0.f;
  #pragma unroll
  for (int q = 0; q < 23; ++q) tailn += wsf[5632 + q * 256 + t];
  float ptil = ALPHA_BF - (s + b2[t] * Sy);
  float cert = fmaf(fmaf(3.0f, tailn, 3e-3f * wsf[11520 + t]), SyA, 128.0f);
  int ok = ((ptil - cert) >= 0.f) ? 1 : 0;        // NaN -> 0
  __shared__ int smi[256];
  __shared__ int okk;
  smi[t] = ok;
  __syncthreads();
  for (int off = 128; off > 0; off >>= 1) {
    if (t < off) smi[t] = smi[t] & smi[t + off];
    __syncthreads();
  }
  if (t == 0) {
    float Xo = __uint_as_float(*reinterpret_cast<unsigned int*>(&wsf[1]));
    okk = (smi[0] && (Xo <= XFIX)) ? 1 : 0;
    if (blockIdx.x == 0) wsf[0] = okk ? 1.f : 0.f;   // flag for fallback
  }
  __syncthreads();
  if (!okk) return;
  int i = blockIdx.x * 256 + t;                   // 257 blocks = 65792 exactly
  if (i < BATCHN + NF) out[i] = 0.f;              // exact zeros
}

// ---------------- fb_all: entire exact fallback in ONE node ------------------
// flag==1 (always, for bench inputs): every block exits immediately.
// flag==0: 2048 blocks compute exact zty partials; the LAST block to finish
// (device-scope ticket) serially completes p, Q, Cholesky, QP, yhat.
// Correctness-only path -- speed irrelevant; no spin-waits (deadlock-free).
__global__ __launch_bounds__(256) void fb_all_kernel(
    const float* __restrict__ x, const float* __restrict__ y,
    const float* __restrict__ W1, const float* __restrict__ b1,
    const float* __restrict__ W2, const float* __restrict__ b2,
    float* __restrict__ wsf, float* __restrict__ out)
{
  if (wsf[0] >= 0.5f) return;                     // certified zero path taken
  const int t = threadIdx.x;
  float* fb_part = wsf + 552960;
  float* p_ex    = wsf + 1077248;
  float* Q       = wsf + 1077504;
  float* L       = Q + 65536;
  float* Qe      = L + 65536;
  // phase 1: exact Z^T y partials (32 rows per block)
  {
    const int b0 = blockIdx.x * 32;
    float zty = 0.f;
    for (int r = 0; r < 32; ++r) {
      float xv = x[(size_t)(b0 + r) * NF + t];
      zty = fmaf(zeval(W1, b1, W2, b2, t, xv), y[b0 + r], zty);
    }
    fb_part[(size_t)blockIdx.x * NF + t] = zty;
  }
  __threadfence();
  __shared__ unsigned int tick;
  if (t == 0)
    tick = atomicAdd(reinterpret_cast<unsigned int*>(&wsf[2]), 1u);
  __syncthreads();
  if (tick != 2047u) return;
  // ---- last block: serial completion ----
  {
    float s = 0.f;
    for (int j = 0; j < 2048; ++j) s += fb_part[(size_t)j * NF + t];
    p_ex[t] = ALPHA_BF - s;
  }
  for (int i = t; i < 65536; i += 256)
    Q[i] = ((i >> 8) == (i & 255)) ? JITTERF : 0.f;
  __syncthreads();
  __shared__ float zsh[16 * NF];                  // 16 KiB chunks of Z
  for (int c = 0; c < BATCHN / 16; ++c) {
    const int r0 = c * 16;
    for (int r = 0; r < 16; ++r)
      zsh[r * NF + t] = zeval(W1, b1, W2, b2, t, x[(size_t)(r0 + r) * NF + t]);
    __syncthreads();
    for (int j = 0; j < NF; ++j) {
      float s = 0.f;
      for (int r = 0; r < 16; ++r) s += zsh[r * NF + t] * zsh[r * NF + j];
      Q[t * NF + j] += s;
    }
    __syncthreads();
  }
  // right-looking Cholesky -> Qe = L L^T
  __shared__ float sm[NF];
  __shared__ float lam_s[NF];
  for (int i = 0; i < NF; ++i) L[i * NF + t] = (t <= i) ? Q[i * NF + t] : 0.f;
  __syncthreads();
  for (int k = 0; k < NF; ++k) {
    if (t == 0) L[k * NF + k] = sqrtf(L[k * NF + k]);
    __syncthreads();
    float lkk = L[k * NF + k];
    if (t > k) L[t * NF + k] /= lkk;
    __syncthreads();
    if (t > k) {
      float ltk = L[t * NF + k];
      for (int i = k + 1; i <= t; ++i) L[t * NF + i] -= ltk * L[i * NF + k];
    }
    __syncthreads();
  }
  for (int i = 0; i < NF; ++i) {
    int m = (i < t) ? i : t;
    float s = 0.f;
    for (int k = 0; k <= m; ++k) s += L[i * NF + k] * L[t * NF + k];
    Qe[i * NF + t] = s;
  }
  __syncthreads();
  lam_s[t] = 1.f;
  __syncthreads();
  float lmax = 1.f;
  for (int it = 0; it < 256; ++it) {              // power iteration
    float s = 0.f;
    for (int k = 0; k < NF; ++k) s += Qe[t * NF + k] * lam_s[k];
    sm[t] = s * s;
    __syncthreads();
    for (int off = 128; off > 0; off >>= 1) {
      if (t < off) sm[t] += sm[t + off];
      __syncthreads();
    }
    float nrm = sqrtf(sm[0]);
    __syncthreads();
    lam_s[t] = s / nrm;
    lmax = nrm;
    __syncthreads();
  }
  float step = 1.0f / lmax;
  lam_s[t] = 0.f;
  __syncthreads();
  float pv = p_ex[t];
  for (int it = 0; it < QP_ITERS_N; ++it) {       // projected gradient
    float s = 0.f;
    for (int k = 0; k < NF; ++k) s += Qe[t * NF + k] * lam_s[k];
    float ln = fmaxf(lam_s[t] - step * (s + pv), 0.f);
    __syncthreads();
    lam_s[t] = ln;
    __syncthreads();
  }
  out[BATCHN + t] = lam_s[t];
  __syncthreads();
  for (int b = t; b < BATCHN; b += 256) {         // y_hat = Z @ lam
    float acc = 0.f;
    for (int n = 0; n < NF; ++n)
      acc = fmaf(zeval(W1, b1, W2, b2, n, x[(size_t)b * NF + n]),
                 lam_s[n], acc);
    out[b] = acc;
  }
}

// ---------------- host launcher ---------------------------------------------
extern "C" void kernel_launch(void* const* d_in, const int* in_sizes, int n_in,
                              void* d_out, int out_size, void* d_ws, size_t ws_size,
                              hipStream_t stream) {
  const float* x  = (const float*)d_in[0];
  const float* y  = (const float*)d_in[1];
  const float* W1 = (const float*)d_in[2];
  const float* b1 = (const float*)d_in[3];
  const float* W2 = (const float*)d_in[4];
  const float* b2 = (const float*)d_in[5];
  float* out = (float*)d_out;            // [0,65536): y_hat ; [65536,65792): lam
  float* ws  = (float*)d_ws;

  // fast certified path (4 nodes) + single-node fallback
  mcoeff_kernel<<<1472, 256, 0, stream>>>(y, W1, b1, W2, ws);
  zmom_kernel<<<2048, 256, 0, stream>>>(x, y, ws);
  red1f_kernel<<<64, 256, 0, stream>>>(ws);
  zwflag_kernel<<<257, 256, 0, stream>>>(b2, ws, out);
  fb_all_kernel<<<2048, 256, 0, stream>>>(x, y, W1, b1, W2, b2, ws, out);
}

// Round 21
// 45.870 us; speedup vs baseline: 2.7052x; 1.2212x over previous
//
#include <hip/hip_runtime.h>
#include <math.h>

// DifferentiableLassoSelector: B=65536, n=256, h=32.
// p = 6553.6 - Z^T y > 0 elementwise (~40 sigma margin) => projected-gradient
// QP stays at lam=0 exactly => y_hat = 0 exactly.
// Chebyshev factorization, h pre-combined: C_k[n] = sum_h W2 c_k[n,h];
// z~[b,n] = sum_k C_k T_k(x/X); zty[n] = sum_b y z~.
// r20 post-mortem: LDS staging (decouples load depth from the VGPR
// allocator) works but __syncthreads drains vmcnt(0) -> depth-1 pipeline,
// ~170cy compute per ~500-900cy stall. r21: 1024 blocks x 64 rows, 8-row
// chunks (2 global_load_lds per wave per chunk) -> compute/barrier doubles,
// per-block prologue halves, grid = exactly 4 blocks/CU.
// Certification gates the zero path; exact fallback is one flag-guarded
// kernel (last-block-done ticket).

#define NF 256
#define HID 32
#define BATCHN 65536
#define ALPHA_BF 6553.6f               // ALPHA * BATCH
#define JITTERF 1e-4f
#define QP_ITERS_N 500
#define K2C 2.8853900817779268f        // 2*log2(e): exp2(K2C*u) = e^{2u}
#define XFIX 6.5f
#define INVX (1.0f / 6.5f)
#define NNODE 44                       // Chebyshev nodes; coeffs k=0..43
// ws float layout:
// 0: flagA | 1: Xobs bits | 2: ticket | 8..72: ypart[64] | 72..136: yabspart
// 256:     Carr[21][256]     -> 5632
// 5632:    tailpart[23][256] -> 11520
// 11520:   sw2[256]          -> 11776
// 12288:   part2[64][256]    -> 28672
// 28672:   part[1024][256]   -> 290816
// 552960:  fb_part[2048][256]-> 1077248
// 1077248: p_ex[256]         -> 1077504
// 1077504: Q | L | Qe        -> 1274112  (~5.1 MB total)

#if __has_builtin(__builtin_amdgcn_exp2f)
__device__ __forceinline__ float fexp2(float x) { return __builtin_amdgcn_exp2f(x); }
#else
__device__ __forceinline__ float fexp2(float x) { return exp2f(x); }
#endif
#if __has_builtin(__builtin_amdgcn_rcpf)
__device__ __forceinline__ float frcp(float x) { return __builtin_amdgcn_rcpf(x); }
#else
__device__ __forceinline__ float frcp(float x) { return 1.0f / x; }
#endif

// async global->LDS stage of 16B/lane (1KB/wave): LDS dest is wave-uniform,
// HW scatters lane l to ldst + l*16. Fallback: reg-relay with same layout.
#if __has_builtin(__builtin_amdgcn_global_load_lds)
#define STAGE_ROW(gsrc, ldst, lane) \
  __builtin_amdgcn_global_load_lds( \
      (const __attribute__((address_space(1))) void*)(gsrc), \
      (__attribute__((address_space(3))) void*)(ldst), 16, 0, 0)
#else
#define STAGE_ROW(gsrc, ldst, lane) \
  do { *reinterpret_cast<float4*>((float*)(ldst) + (lane) * 4) = \
       *reinterpret_cast<const float4*>(gsrc); } while (0)
#endif

// exact per-feature MLP output z[b,n] (fallback path only; perf-irrelevant)
__device__ __forceinline__ float zeval(const float* __restrict__ W1,
                                       const float* __restrict__ b1,
                                       const float* __restrict__ W2,
                                       const float* __restrict__ b2,
                                       int n, float xv)
{
  float acc = b2[n];
  for (int h = 0; h < HID; ++h) {
    float u  = fmaf(xv, W1[n * HID + h], b1[n * HID + h]);
    float th = fmaf(-2.f, frcp(fexp2(K2C * u) + 1.f), 1.f);   // exact tanh
    acc = fmaf(W2[n * HID + h], th, acc);
  }
  return acc;
}

// ---------------- mcoeff: ysum (blocks 0..63) + combined coeffs (64..1471) ---
__global__ __launch_bounds__(256) void mcoeff_kernel(
    const float* __restrict__ y,
    const float* __restrict__ W1, const float* __restrict__ b1,
    const float* __restrict__ W2, float* __restrict__ wsf)
{
  const int t = threadIdx.x;
  if ((int)blockIdx.x < 64) {
    // ---- ysum role: per-block partial sums of y and |y| ----
    const int gi = blockIdx.x * 256 + t;
    if (gi == 0) wsf[1] = 0.f;                  // Xobs (atomicMax target)
    if (gi == 2) wsf[2] = 0.f;                  // fallback ticket
    float4 v = *reinterpret_cast<const float4*>(y + gi * 4);
    float s  = (v.x + v.y) + (v.z + v.w);
    float sa = (fabsf(v.x) + fabsf(v.y)) + (fabsf(v.z) + fabsf(v.w));
    #pragma unroll
    for (int m = 1; m < 64; m <<= 1) {
      s  += __shfl_xor(s, m);
      sa += __shfl_xor(sa, m);
    }
    __shared__ float ls[4], la[4];
    int w = t >> 6;
    if ((t & 63) == 0) { ls[w] = s; la[w] = sa; }
    __syncthreads();
    if (t == 0) {
      wsf[8  + blockIdx.x] = (ls[0] + ls[1]) + (ls[2] + ls[3]);
      wsf[72 + blockIdx.x] = (la[0] + la[1]) + (la[2] + la[3]);
    }
  } else {
    // ---- coeff role: thread = (id, k); h-reduced combined coefficients ----
    const int cb = blockIdx.x - 64;            // [0, 1408)
    const int k  = cb >> 5;                    // 0..43
    const int id = (cb & 31) * 256 + t;        // 0..8191 = n*32+h
    const int h  = t & 31;
    const int n  = id >> 5;
    const float aX  = W1[id] * XFIX;
    const float bb  = b1[id];
    const float w2v = W2[id];
    const float kf = (float)k;
    const float C1 = (float)(M_PI / (double)NNODE);
    float acc = 0.f;
    #pragma unroll 4
    for (int jn = 0; jn < NNODE; ++jn) {
      float ang = ((float)jn + 0.5f) * C1;
      float tj  = __cosf(ang);
      float u   = fmaf(aX, tj, bb);
      float f   = fmaf(-2.f, frcp(fexp2(K2C * u) + 1.f), 1.f);  // exact tanh
      acc = fmaf(f, __cosf(kf * ang), acc);
    }
    const float ck = acc * ((k == 0) ? (1.0f / (float)NNODE)
                                     : (2.0f / (float)NNODE));
    float comb = w2v * ck;                     // signed, for C_k[n]
    float cabs = fabsf(comb);                  // |W2 c_k|, for tail
    float wabs = fabsf(w2v);                   // |W2|, for k==0 slack
    #pragma unroll
    for (int m = 1; m < 32; m <<= 1) {         // reduce over h (32 lanes)
      comb += __shfl_xor(comb, m);
      cabs += __shfl_xor(cabs, m);
      wabs += __shfl_xor(wabs, m);
    }
    if (h == 0) {
      if (k <= 20) wsf[256 + k * 256 + n] = comb;
      else         wsf[5632 + (k - 21) * 256 + n] = cabs;
      if (k == 0)  wsf[11520 + n] = wabs;
    }
  }
}

// ---------------- zmom: LDS-staged, 8-row chunks, 1024 blocks x 64 rows ------
#define STEP1(CK) { float q = fmaf(dd, Tc, -Tm); \
  a = fmaf(CK, q, a); Tm = Tc; Tc = q; }

__global__ __launch_bounds__(256, 4) void zmom_kernel(
    const float* __restrict__ x, const float* __restrict__ y,
    float* __restrict__ wsf)
{
  const int t = threadIdx.x;                // feature n == t
  const int lane = t & 63, wv = t >> 6;
  __shared__ float xbuf[2][8][NF];          // 16 KB: 2 bufs x 8 rows x 1KB
  const float* Carr = wsf + 256;
  const float c00 = Carr[t],            c01 = Carr[256 + t];
  const float c02 = Carr[512 + t],      c03 = Carr[768 + t];
  const float c04 = Carr[1024 + t],     c05 = Carr[1280 + t];
  const float c06 = Carr[1536 + t],     c07 = Carr[1792 + t];
  const float c08 = Carr[2048 + t],     c09 = Carr[2304 + t];
  const float c10 = Carr[2560 + t],     c11 = Carr[2816 + t];
  const float c12 = Carr[3072 + t],     c13 = Carr[3328 + t];
  const float c14 = Carr[3584 + t],     c15 = Carr[3840 + t];
  const float c16 = Carr[4096 + t],     c17 = Carr[4352 + t];
  const float c18 = Carr[4608 + t],     c19 = Carr[4864 + t];
  const float c20 = Carr[5120 + t];
  const int b0 = blockIdx.x * 64;           // 1024 blocks x 64 rows
  // prologue: wave wv stages rows {2wv, 2wv+1} of chunk 0 (2 instr = 2KB)
  STAGE_ROW(x + (size_t)(b0 + 2 * wv) * NF + lane * 4,
            &xbuf[0][2 * wv][0], lane);
  STAGE_ROW(x + (size_t)(b0 + 2 * wv + 1) * NF + lane * 4,
            &xbuf[0][2 * wv + 1][0], lane);
  __syncthreads();                          // drains vmcnt -> buf0 ready
  float z0 = 0.f, mx = 0.f;
  for (int c = 0; c < 8; ++c) {             // 8 chunks x 8 rows
    if (c < 7) {
      const int r0 = b0 + (c + 1) * 8 + 2 * wv;
      STAGE_ROW(x + (size_t)r0 * NF + lane * 4,
                &xbuf[(c + 1) & 1][2 * wv][0], lane);
      STAGE_ROW(x + (size_t)(r0 + 1) * NF + lane * 4,
                &xbuf[(c + 1) & 1][2 * wv + 1][0], lane);
    }
    const float* xb = &xbuf[c & 1][0][0];
    const float* yb = y + b0 + c * 8;
    #pragma unroll
    for (int r = 0; r < 8; ++r) {           // 8 independent rows (ILP)
      float xv = xb[r * NF + t];            // ds_read, 2-way bank = free
      float yv = yb[r];                     // uniform -> scalar load
      mx = fmaxf(mx, fabsf(xv));
      float h = xv * INVX;
      float dd = h + h;
      float Tm = 1.f, Tc = h;
      float a = fmaf(c01, h, c00);
      STEP1(c02) STEP1(c03) STEP1(c04) STEP1(c05) STEP1(c06) STEP1(c07)
      STEP1(c08) STEP1(c09) STEP1(c10) STEP1(c11) STEP1(c12) STEP1(c13)
      STEP1(c14) STEP1(c15) STEP1(c16) STEP1(c17) STEP1(c18) STEP1(c19)
      STEP1(c20)
      z0 = fmaf(a, yv, z0);
    }
    __syncthreads();                        // drains next-chunk stage + sync
  }
  // |x| max: wave-reduce, block-reduce, ONE atomic per block (order-exact)
  #pragma unroll
  for (int m = 1; m < 64; m <<= 1) mx = fmaxf(mx, __shfl_xor(mx, m));
  __shared__ float wmx[4];
  if (lane == 0) wmx[wv] = mx;
  __syncthreads();
  if (t == 0) {
    float m4 = fmaxf(fmaxf(wmx[0], wmx[1]), fmaxf(wmx[2], wmx[3]));
    atomicMax(reinterpret_cast<unsigned int*>(&wsf[1]), __float_as_uint(m4));
  }
  wsf[28672 + (size_t)blockIdx.x * NF + t] = z0;  // coalesced 1KB/blk
}

// ---------------- red1f: part[1024][256] -> part2[64][256] -------------------
__global__ __launch_bounds__(256) void red1f_kernel(float* __restrict__ wsf)
{
  const int n = threadIdx.x, j = blockIdx.x;      // 64 blocks x 16 slices
  const float* p = wsf + 28672 + (size_t)j * 16 * NF + n;
  float s0 = 0.f, s1 = 0.f, s2 = 0.f, s3 = 0.f;
  #pragma unroll
  for (int k = 0; k < 16; k += 4) {
    s0 += p[(size_t)k * NF];       s1 += p[(size_t)(k + 1) * NF];
    s2 += p[(size_t)(k + 2) * NF]; s3 += p[(size_t)(k + 3) * NF];
  }
  wsf[12288 + (size_t)j * NF + n] = (s0 + s1) + (s2 + s3);
}

// ---------------- zwflag: redundant flag computation + zero-write ------------
__global__ __launch_bounds__(256) void zwflag_kernel(
    const float* __restrict__ b2, float* __restrict__ wsf,
    float* __restrict__ out)
{
  const int t = threadIdx.x;                      // t == feature n
  __shared__ float shv[2];
  if (t < 64) {
    float a = wsf[8 + t], bb = wsf[72 + t];
    #pragma unroll
    for (int m = 1; m < 64; m <<= 1) {
      a  += __shfl_xor(a, m);
      bb += __shfl_xor(bb, m);
    }
    if (t == 0) { shv[0] = a; shv[1] = bb; }
  }
  __syncthreads();
  const float Sy = shv[0], SyA = shv[1];
  float s = 0.f;
  #pragma unroll
  for (int j = 0; j < 64; ++j) s += wsf[12288 + j * NF + t];
  float tailn = 0.f;
  #pragma unroll
  for (int q = 0; q < 23; ++q) tailn += wsf[5632 + q * 256 + t];
  float ptil = ALPHA_BF - (s + b2[t] * Sy);
  float cert = fmaf(fmaf(3.0f, tailn, 3e-3f * wsf[11520 + t]), SyA, 128.0f);
  int ok = ((ptil - cert) >= 0.f) ? 1 : 0;        // NaN -> 0
  __shared__ int smi[256];
  __shared__ int okk;
  smi[t] = ok;
  __syncthreads();
  for (int off = 128; off > 0; off >>= 1) {
    if (t < off) smi[t] = smi[t] & smi[t + off];
    __syncthreads();
  }
  if (t == 0) {
    float Xo = __uint_as_float(*reinterpret_cast<unsigned int*>(&wsf[1]));
    okk = (smi[0] && (Xo <= XFIX)) ? 1 : 0;
    if (blockIdx.x == 0) wsf[0] = okk ? 1.f : 0.f;   // flag for fallback
  }
  __syncthreads();
  if (!okk) return;
  int i = blockIdx.x * 256 + t;                   // 257 blocks = 65792 exactly
  if (i < BATCHN + NF) out[i] = 0.f;              // exact zeros
}

// ---------------- fb_all: entire exact fallback in ONE node ------------------
// flag==1 (always, for bench inputs): every block exits immediately.
// flag==0: 2048 blocks compute exact zty partials; the LAST block to finish
// (device-scope ticket) serially completes p, Q, Cholesky, QP, yhat.
// Correctness-only path -- speed irrelevant; no spin-waits (deadlock-free).
__global__ __launch_bounds__(256) void fb_all_kernel(
    const float* __restrict__ x, const float* __restrict__ y,
    const float* __restrict__ W1, const float* __restrict__ b1,
    const float* __restrict__ W2, const float* __restrict__ b2,
    float* __restrict__ wsf, float* __restrict__ out)
{
  if (wsf[0] >= 0.5f) return;                     // certified zero path taken
  const int t = threadIdx.x;
  float* fb_part = wsf + 552960;
  float* p_ex    = wsf + 1077248;
  float* Q       = wsf + 1077504;
  float* L       = Q + 65536;
  float* Qe      = L + 65536;
  // phase 1: exact Z^T y partials (32 rows per block)
  {
    const int b0 = blockIdx.x * 32;
    float zty = 0.f;
    for (int r = 0; r < 32; ++r) {
      float xv = x[(size_t)(b0 + r) * NF + t];
      zty = fmaf(zeval(W1, b1, W2, b2, t, xv), y[b0 + r], zty);
    }
    fb_part[(size_t)blockIdx.x * NF + t] = zty;
  }
  __threadfence();
  __shared__ unsigned int tick;
  if (t == 0)
    tick = atomicAdd(reinterpret_cast<unsigned int*>(&wsf[2]), 1u);
  __syncthreads();
  if (tick != 2047u) return;
  // ---- last block: serial completion ----
  {
    float s = 0.f;
    for (int j = 0; j < 2048; ++j) s += fb_part[(size_t)j * NF + t];
    p_ex[t] = ALPHA_BF - s;
  }
  for (int i = t; i < 65536; i += 256)
    Q[i] = ((i >> 8) == (i & 255)) ? JITTERF : 0.f;
  __syncthreads();
  __shared__ float zsh[16 * NF];                  // 16 KiB chunks of Z
  for (int c = 0; c < BATCHN / 16; ++c) {
    const int r0 = c * 16;
    for (int r = 0; r < 16; ++r)
      zsh[r * NF + t] = zeval(W1, b1, W2, b2, t, x[(size_t)(r0 + r) * NF + t]);
    __syncthreads();
    for (int j = 0; j < NF; ++j) {
      float s = 0.f;
      for (int r = 0; r < 16; ++r) s += zsh[r * NF + t] * zsh[r * NF + j];
      Q[t * NF + j] += s;
    }
    __syncthreads();
  }
  // right-looking Cholesky -> Qe = L L^T
  __shared__ float sm[NF];
  __shared__ float lam_s[NF];
  for (int i = 0; i < NF; ++i) L[i * NF + t] = (t <= i) ? Q[i * NF + t] : 0.f;
  __syncthreads();
  for (int k = 0; k < NF; ++k) {
    if (t == 0) L[k * NF + k] = sqrtf(L[k * NF + k]);
    __syncthreads();
    float lkk = L[k * NF + k];
    if (t > k) L[t * NF + k] /= lkk;
    __syncthreads();
    if (t > k) {
      float ltk = L[t * NF + k];
      for (int i = k + 1; i <= t; ++i) L[t * NF + i] -= ltk * L[i * NF + k];
    }
    __syncthreads();
  }
  for (int i = 0; i < NF; ++i) {
    int m = (i < t) ? i : t;
    float s = 0.f;
    for (int k = 0; k <= m; ++k) s += L[i * NF + k] * L[t * NF + k];
    Qe[i * NF + t] = s;
  }
  __syncthreads();
  lam_s[t] = 1.f;
  __syncthreads();
  float lmax = 1.f;
  for (int it = 0; it < 256; ++it) {              // power iteration
    float s = 0.f;
    for (int k = 0; k < NF; ++k) s += Qe[t * NF + k] * lam_s[k];
    sm[t] = s * s;
    __syncthreads();
    for (int off = 128; off > 0; off >>= 1) {
      if (t < off) sm[t] += sm[t + off];
      __syncthreads();
    }
    float nrm = sqrtf(sm[0]);
    __syncthreads();
    lam_s[t] = s / nrm;
    lmax = nrm;
    __syncthreads();
  }
  float step = 1.0f / lmax;
  lam_s[t] = 0.f;
  __syncthreads();
  float pv = p_ex[t];
  for (int it = 0; it < QP_ITERS_N; ++it) {       // projected gradient
    float s = 0.f;
    for (int k = 0; k < NF; ++k) s += Qe[t * NF + k] * lam_s[k];
    float ln = fmaxf(lam_s[t] - step * (s + pv), 0.f);
    __syncthreads();
    lam_s[t] = ln;
    __syncthreads();
  }
  out[BATCHN + t] = lam_s[t];
  __syncthreads();
  for (int b = t; b < BATCHN; b += 256) {         // y_hat = Z @ lam
    float acc = 0.f;
    for (int n = 0; n < NF; ++n)
      acc = fmaf(zeval(W1, b1, W2, b2, n, x[(size_t)b * NF + n]),
                 lam_s[n], acc);
    out[b] = acc;
  }
}

// ---------------- host launcher ---------------------------------------------
extern "C" void kernel_launch(void* const* d_in, const int* in_sizes, int n_in,
                              void* d_out, int out_size, void* d_ws, size_t ws_size,
                              hipStream_t stream) {
  const float* x  = (const float*)d_in[0];
  const float* y  = (const float*)d_in[1];
  const float* W1 = (const float*)d_in[2];
  const float* b1 = (const float*)d_in[3];
  const float* W2 = (const float*)d_in[4];
  const float* b2 = (const float*)d_in[5];
  float* out = (float*)d_out;            // [0,65536): y_hat ; [65536,65792): lam
  float* ws  = (float*)d_ws;

  // fast certified path (4 nodes) + single-node fallback
  mcoeff_kernel<<<1472, 256, 0, stream>>>(y, W1, b1, W2, ws);
  zmom_kernel<<<1024, 256, 0, stream>>>(x, y, ws);
  red1f_kernel<<<64, 256, 0, stream>>>(ws);
  zwflag_kernel<<<257, 256, 0, stream>>>(b2, ws, out);
  fb_all_kernel<<<2048, 256, 0, stream>>>(x, y, W1, b1, W2, b2, ws, out);
}